// Round 1
// baseline (250.922 us; speedup 1.0000x reference)
//
#include <hip/hip_runtime.h>

typedef __attribute__((ext_vector_type(8))) short bf16x8;
typedef __attribute__((ext_vector_type(4))) float f32x4;
typedef __attribute__((ext_vector_type(4))) float float4v;
typedef __attribute__((ext_vector_type(4))) unsigned short ushort4v;
typedef __attribute__((ext_vector_type(8))) unsigned short ushort8v;

#define DEVINL __device__ __forceinline__

// B=8, C=768, T=1024, heads=12, ch=64, EC=768, S_enc=256, S_tot=1280, groups=32 (24 ch/group)

DEVINL unsigned short f2bf(float f) {
  union { float f; unsigned u; } v; v.f = f;
  unsigned r = (v.u + 0x7fffu + ((v.u >> 16) & 1u)) >> 16;  // RNE
  return (unsigned short)r;
}

// ---------------- fp32 -> bf16 weight convert ----------------
__global__ __launch_bounds__(256) void k_cvt(const float* __restrict__ s,
                                             unsigned short* __restrict__ d, int n4) {
  int i = blockIdx.x * 256 + threadIdx.x;
  if (i >= n4) return;
  float4v v = *(const float4v*)(s + (size_t)i * 4);
  ushort4v o;
  o[0] = f2bf(v[0]); o[1] = f2bf(v[1]); o[2] = f2bf(v[2]); o[3] = f2bf(v[3]);
  *(ushort4v*)(d + (size_t)i * 4) = o;
}

// ---------------- GroupNorm + transpose -> xn_t[b][t][c] bf16 ----------------
__global__ __launch_bounds__(256) void k_gn(const float* __restrict__ x,
                                            const float* __restrict__ gw,
                                            const float* __restrict__ gb,
                                            unsigned short* __restrict__ xnt) {
  int g = blockIdx.x, b = blockIdx.y, tid = threadIdx.x;
  const float* xb = x + ((size_t)b * 768 + g * 24) * 1024;  // contiguous 24*1024 block
  float s = 0.f, ss = 0.f;
  for (int i = tid; i < 6144; i += 256) {  // 24576 floats as float4
    float4v v = *(const float4v*)(xb + (size_t)i * 4);
    s += v[0] + v[1] + v[2] + v[3];
    ss += v[0] * v[0] + v[1] * v[1] + v[2] * v[2] + v[3] * v[3];
  }
  #pragma unroll
  for (int o = 32; o > 0; o >>= 1) { s += __shfl_down(s, o); ss += __shfl_down(ss, o); }
  __shared__ float rs[4], rss[4], stat[2];
  int w = tid >> 6;
  if ((tid & 63) == 0) { rs[w] = s; rss[w] = ss; }
  __syncthreads();
  if (tid == 0) {
    float S = rs[0] + rs[1] + rs[2] + rs[3], SS = rss[0] + rss[1] + rss[2] + rss[3];
    float mean = S / 24576.f;
    float var = SS / 24576.f - mean * mean;
    stat[0] = mean; stat[1] = rsqrtf(fmaxf(var, 0.f) + 1e-5f);
  }
  __syncthreads();
  float mean = stat[0], rstd = stat[1];
  float wv[24], bv[24];
  #pragma unroll
  for (int c = 0; c < 24; ++c) { wv[c] = gw[g * 24 + c]; bv[c] = gb[g * 24 + c]; }
  for (int it = 0; it < 4; ++it) {
    int t = it * 256 + tid;
    ushort8v ov[3];
    #pragma unroll
    for (int c = 0; c < 24; ++c) {
      float v = xb[(size_t)c * 1024 + t];
      ov[c >> 3][c & 7] = f2bf((v - mean) * rstd * wv[c] + bv[c]);
    }
    ushort8v* dst = (ushort8v*)(xnt + ((size_t)(b * 1024 + t)) * 768 + g * 24);
    dst[0] = ov[0]; dst[1] = ov[1]; dst[2] = ov[2];
  }
}

// ---------------- encoder transpose -> enc_t[b][s][c] bf16 ----------------
__global__ __launch_bounds__(256) void k_enc_tr(const float* __restrict__ enc,
                                                unsigned short* __restrict__ et) {
  int ct = blockIdx.x * 64, st = blockIdx.y * 64, b = blockIdx.z, tid = threadIdx.x;
  __shared__ unsigned short L[64 * 72];
  #pragma unroll
  for (int it = 0; it < 4; ++it) {
    int idx = it * 256 + tid; int r = idx >> 4, ch = idx & 15;
    float4v v = *(const float4v*)(enc + ((size_t)(b * 768 + ct + r)) * 256 + st + ch * 4);
    ushort4v o;
    o[0] = f2bf(v[0]); o[1] = f2bf(v[1]); o[2] = f2bf(v[2]); o[3] = f2bf(v[3]);
    *(ushort4v*)&L[r * 72 + ch * 4] = o;
  }
  __syncthreads();
  #pragma unroll
  for (int it = 0; it < 2; ++it) {
    int idx = it * 256 + tid; int s = idx >> 3, ch = idx & 7;
    ushort8v o;
    #pragma unroll
    for (int j = 0; j < 8; ++j) o[j] = L[(ch * 8 + j) * 72 + s];
    *(ushort8v*)(et + ((size_t)(b * 256 + st + s)) * 768 + ct + ch * 8) = o;
  }
}

// ---------------- build vcat[bh][c][s] bf16 (transpose of v slices) ----------------
__global__ __launch_bounds__(256) void k_vcat(const unsigned short* __restrict__ qkvt,
                                              const unsigned short* __restrict__ ekvt,
                                              unsigned short* __restrict__ vcat) {
  int s0 = blockIdx.x * 64, bh = blockIdx.y, b = bh / 12, h = bh % 12, tid = threadIdx.x;
  __shared__ unsigned short L[64 * 72];
  #pragma unroll
  for (int it = 0; it < 2; ++it) {
    int idx = it * 256 + tid; int s = idx >> 3, ch = idx & 7;
    int sg = s0 + s;
    const unsigned short* src = (sg < 256)
        ? ekvt + ((size_t)(b * 256 + sg)) * 1536 + h * 128 + 64 + ch * 8
        : qkvt + ((size_t)(b * 1024 + sg - 256)) * 2304 + h * 192 + 128 + ch * 8;
    *(ushort8v*)&L[s * 72 + ch * 8] = *(const ushort8v*)src;
  }
  __syncthreads();
  #pragma unroll
  for (int it = 0; it < 2; ++it) {
    int idx = it * 256 + tid; int c = idx >> 3, ch = idx & 7;
    ushort8v o;
    #pragma unroll
    for (int j = 0; j < 8; ++j) o[j] = L[(ch * 8 + j) * 72 + c];
    *(ushort8v*)(vcat + ((size_t)bh * 64 + c) * 1280 + s0 + ch * 8) = o;
  }
}

// ---------------- GEMM (bt form): C[M][N] = A[M][K] * B[N][K]^T ----------------
// EPI 0: out bf16, bias[col]   EPI 1: out fp32, bias[row] + resid
template <int EPI>
__global__ __launch_bounds__(256) void k_gemm(const unsigned short* __restrict__ A,
                                              const unsigned short* __restrict__ B,
                                              const float* __restrict__ bias,
                                              const float* __restrict__ resid,
                                              void* __restrict__ outp,
                                              int N, int K,
                                              long sA, long sB, long sO, long sR) {
  int bz = blockIdx.z;
  const unsigned short* Ab = A + (size_t)bz * sA;
  const unsigned short* Bb = B + (size_t)bz * sB;
  int m0 = blockIdx.x * 128, n0 = blockIdx.y * 128;
  __shared__ unsigned short As[128 * 40], Bs[128 * 40];
  int tid = threadIdx.x, lane = tid & 63, w = tid >> 6;
  int ln = lane & 15, lg = lane >> 4;
  int wm = (w >> 1) * 64, wn = (w & 1) * 64;
  f32x4 acc[4][4];
  #pragma unroll
  for (int i = 0; i < 4; ++i)
    #pragma unroll
    for (int j = 0; j < 4; ++j) acc[i][j] = (f32x4){0.f, 0.f, 0.f, 0.f};

  for (int k0 = 0; k0 < K; k0 += 32) {
    #pragma unroll
    for (int it = 0; it < 2; ++it) {
      int idx = it * 256 + tid; int r = idx >> 2, c = idx & 3;
      *(bf16x8*)&As[r * 40 + c * 8] = *(const bf16x8*)&Ab[(size_t)(m0 + r) * K + k0 + c * 8];
      *(bf16x8*)&Bs[r * 40 + c * 8] = *(const bf16x8*)&Bb[(size_t)(n0 + r) * K + k0 + c * 8];
    }
    __syncthreads();
    bf16x8 af[4], bfv[4];
    #pragma unroll
    for (int i = 0; i < 4; ++i) af[i] = *(const bf16x8*)&As[(wm + i * 16 + ln) * 40 + lg * 8];
    #pragma unroll
    for (int i = 0; i < 4; ++i) bfv[i] = *(const bf16x8*)&Bs[(wn + i * 16 + ln) * 40 + lg * 8];
    #pragma unroll
    for (int i = 0; i < 4; ++i)
      #pragma unroll
      for (int j = 0; j < 4; ++j)
        acc[i][j] = __builtin_amdgcn_mfma_f32_16x16x32_bf16(af[i], bfv[j], acc[i][j], 0, 0, 0);
    __syncthreads();
  }

  #pragma unroll
  for (int i = 0; i < 4; ++i) {
    #pragma unroll
    for (int j = 0; j < 4; ++j) {
      #pragma unroll
      for (int r = 0; r < 4; ++r) {
        int row = m0 + wm + i * 16 + lg * 4 + r;
        int col = n0 + wn + j * 16 + ln;
        float v = acc[i][j][r];
        if (EPI == 0) {
          v += bias[col];
          ((unsigned short*)outp)[(size_t)bz * sO + (size_t)row * N + col] = f2bf(v);
        } else {
          v += bias[row] + resid[(size_t)bz * sR + (size_t)row * N + col];
          ((float*)outp)[(size_t)bz * sO + (size_t)row * N + col] = v;
        }
      }
    }
  }
}

// ---------------- flash attention: Q-tile 128, S-tile 64, 8 waves ----------------
__global__ __launch_bounds__(512) void k_attn(const unsigned short* __restrict__ qkvt,
                                              const unsigned short* __restrict__ ekvt,
                                              const unsigned short* __restrict__ vcat,
                                              unsigned short* __restrict__ at) {
  int t0 = blockIdx.x * 128, bh = blockIdx.y, b = bh / 12, h = bh % 12;
  int tid = threadIdx.x, w = tid >> 6, lane = tid & 63, ln = lane & 15, lg = lane >> 4;
  __shared__ unsigned short Ks[64 * 72], Vs[64 * 72], Ps[128 * 72];

  const unsigned short* qb = qkvt + ((size_t)(b * 1024 + t0 + w * 16 + ln)) * 2304 + h * 192;
  bf16x8 aq[2];
  aq[0] = *(const bf16x8*)(qb + 0 + lg * 8);
  aq[1] = *(const bf16x8*)(qb + 32 + lg * 8);

  float m[4], l[4];
  f32x4 acc[4];
  #pragma unroll
  for (int r = 0; r < 4; ++r) { m[r] = -1e30f; l[r] = 0.f; }
  #pragma unroll
  for (int c = 0; c < 4; ++c) acc[c] = (f32x4){0.f, 0.f, 0.f, 0.f};

  int sS = tid >> 3, sCh = tid & 7;
  for (int s0 = 0; s0 < 1280; s0 += 64) {
    int sg = s0 + sS;
    const unsigned short* ksrc = (sg < 256)
        ? ekvt + ((size_t)(b * 256 + sg)) * 1536 + h * 128 + sCh * 8
        : qkvt + ((size_t)(b * 1024 + sg - 256)) * 2304 + h * 192 + 64 + sCh * 8;
    *(ushort8v*)&Ks[sS * 72 + sCh * 8] = *(const ushort8v*)ksrc;
    *(ushort8v*)&Vs[sS * 72 + sCh * 8] =
        *(const ushort8v*)(vcat + ((size_t)bh * 64 + sS) * 1280 + s0 + sCh * 8);
    __syncthreads();

    f32x4 sf[4];
    #pragma unroll
    for (int j = 0; j < 4; ++j) sf[j] = (f32x4){0.f, 0.f, 0.f, 0.f};
    #pragma unroll
    for (int kk = 0; kk < 2; ++kk) {
      #pragma unroll
      for (int j = 0; j < 4; ++j) {
        bf16x8 bk = *(const bf16x8*)&Ks[(j * 16 + ln) * 72 + kk * 32 + lg * 8];
        sf[j] = __builtin_amdgcn_mfma_f32_16x16x32_bf16(aq[kk], bk, sf[j], 0, 0, 0);
      }
    }

    // online softmax per row r (row = lg*4+r within wave's 16 t-rows)
    #pragma unroll
    for (int r = 0; r < 4; ++r) {
      float mt = fmaxf(fmaxf(sf[0][r], sf[1][r]), fmaxf(sf[2][r], sf[3][r])) * 0.125f;
      mt = fmaxf(mt, __shfl_xor(mt, 1));
      mt = fmaxf(mt, __shfl_xor(mt, 2));
      mt = fmaxf(mt, __shfl_xor(mt, 4));
      mt = fmaxf(mt, __shfl_xor(mt, 8));
      float mn = fmaxf(m[r], mt);
      float al = __expf(m[r] - mn);
      float rsum = 0.f;
      unsigned short pb[4];
      #pragma unroll
      for (int j = 0; j < 4; ++j) {
        float p = __expf(sf[j][r] * 0.125f - mn);
        rsum += p;
        pb[j] = f2bf(p);
      }
      rsum += __shfl_xor(rsum, 1);
      rsum += __shfl_xor(rsum, 2);
      rsum += __shfl_xor(rsum, 4);
      rsum += __shfl_xor(rsum, 8);
      l[r] = l[r] * al + rsum;
      m[r] = mn;
      #pragma unroll
      for (int c = 0; c < 4; ++c) acc[c][r] *= al;
      int prow = w * 16 + lg * 4 + r;
      #pragma unroll
      for (int j = 0; j < 4; ++j) Ps[prow * 72 + j * 16 + ln] = pb[j];
    }
    __syncthreads();

    // PV: acc[t][c] += P[t][s] * V[c][s]
    #pragma unroll
    for (int ks = 0; ks < 2; ++ks) {
      bf16x8 ap = *(const bf16x8*)&Ps[(w * 16 + ln) * 72 + ks * 32 + lg * 8];
      #pragma unroll
      for (int c = 0; c < 4; ++c) {
        bf16x8 bv = *(const bf16x8*)&Vs[(c * 16 + ln) * 72 + ks * 32 + lg * 8];
        acc[c] = __builtin_amdgcn_mfma_f32_16x16x32_bf16(ap, bv, acc[c], 0, 0, 0);
      }
    }
    __syncthreads();
  }

  #pragma unroll
  for (int c = 0; c < 4; ++c) {
    #pragma unroll
    for (int r = 0; r < 4; ++r) {
      float v = acc[c][r] / l[r];
      at[((size_t)(b * 1024 + t0 + w * 16 + lg * 4 + r)) * 768 + h * 64 + c * 16 + ln] = f2bf(v);
    }
  }
}

// ---------------- launch ----------------
extern "C" void kernel_launch(void* const* d_in, const int* in_sizes, int n_in,
                              void* d_out, int out_size, void* d_ws, size_t ws_size,
                              hipStream_t stream) {
  const float* x      = (const float*)d_in[0];  // (8,768,32,32)
  const float* enc    = (const float*)d_in[1];  // (8,768,256)
  const float* gn_w   = (const float*)d_in[2];
  const float* gn_b   = (const float*)d_in[3];
  const float* qkv_w  = (const float*)d_in[4];  // (2304,768)
  const float* qkv_b  = (const float*)d_in[5];
  const float* enc_w  = (const float*)d_in[6];  // (1536,768)
  const float* enc_b  = (const float*)d_in[7];
  const float* proj_w = (const float*)d_in[8];  // (768,768)
  const float* proj_b = (const float*)d_in[9];
  float* out = (float*)d_out;

  char* ws = (char*)d_ws;
  unsigned short* w_qkv = (unsigned short*)(ws + 0);          // 2304*768
  unsigned short* w_enc = (unsigned short*)(ws + 3538944);    // 1536*768
  unsigned short* w_prj = (unsigned short*)(ws + 5898240);    // 768*768
  unsigned short* xn_t  = (unsigned short*)(ws + 7077888);    // 8*1024*768 (reused as a_t)
  unsigned short* enc_t = (unsigned short*)(ws + 19660800);   // 8*256*768
  unsigned short* qkv_t = (unsigned short*)(ws + 22806528);   // 8*1024*2304
  unsigned short* ekv_t = (unsigned short*)(ws + 60555264);   // 8*256*1536
  unsigned short* vcat  = (unsigned short*)(ws + 66846720);   // 96*64*1280
  unsigned short* a_t   = xn_t;                               // reuse after GEMM1

  // weight converts
  k_cvt<<<1728, 256, 0, stream>>>(qkv_w, w_qkv, 442368);
  k_cvt<<<1152, 256, 0, stream>>>(enc_w, w_enc, 294912);
  k_cvt<<<576, 256, 0, stream>>>(proj_w, w_prj, 147456);
  // groupnorm -> xn_t
  k_gn<<<dim3(32, 8), 256, 0, stream>>>(x, gn_w, gn_b, xn_t);
  // encoder transpose -> enc_t
  k_enc_tr<<<dim3(12, 4, 8), 256, 0, stream>>>(enc, enc_t);
  // GEMM1: qkv_t[b][t][o] ; M=1024 N=2304 K=768
  k_gemm<0><<<dim3(8, 18, 8), 256, 0, stream>>>(xn_t, w_qkv, qkv_b, nullptr, qkv_t,
                                                2304, 768, 786432L, 0L, 2359296L, 0L);
  // GEMM2: ekv_t[b][s][o] ; M=256 N=1536 K=768
  k_gemm<0><<<dim3(2, 12, 8), 256, 0, stream>>>(enc_t, w_enc, enc_b, nullptr, ekv_t,
                                                1536, 768, 196608L, 0L, 393216L, 0L);
  // vcat[bh][c][s]
  k_vcat<<<dim3(20, 96), 256, 0, stream>>>(qkv_t, ekv_t, vcat);
  // attention -> a_t[b][t][C]
  k_attn<<<dim3(8, 96), 512, 0, stream>>>(qkv_t, ekv_t, vcat, a_t);
  // GEMM3: out[b][o][t] = proj(a) + bias + x ; M=768 N=1024 K=768
  k_gemm<1><<<dim3(6, 8, 8), 256, 0, stream>>>(w_prj, a_t, proj_b, x, out,
                                               1024, 768, 0L, 786432L, 786432L, 786432L);
}

// Round 2
// 240.625 us; speedup vs baseline: 1.0428x; 1.0428x over previous
//
#include <hip/hip_runtime.h>

typedef __attribute__((ext_vector_type(8))) short bf16x8;
typedef __attribute__((ext_vector_type(4))) float f32x4;
typedef __attribute__((ext_vector_type(4))) float float4v;
typedef __attribute__((ext_vector_type(4))) unsigned short ushort4v;
typedef __attribute__((ext_vector_type(8))) unsigned short ushort8v;

#define DEVINL __device__ __forceinline__

// B=8, C=768, T=1024, heads=12, ch=64, EC=768, S_enc=256, S_tot=1280, groups=32

DEVINL unsigned short f2bf(float f) {
  union { float f; unsigned u; } v; v.f = f;
  unsigned r = (v.u + 0x7fffu + ((v.u >> 16) & 1u)) >> 16;  // RNE
  return (unsigned short)r;
}
DEVINL unsigned short f2bfr(float f) {  // cheap round (no tie-to-even)
  union { float f; unsigned u; } v; v.f = f;
  return (unsigned short)((v.u + 0x8000u) >> 16);
}
DEVINL float bf2f(unsigned short h) {
  union { unsigned u; float f; } v; v.u = ((unsigned)h) << 16;
  return v.f;
}
DEVINL float exp2a(float x) {
#if __has_builtin(__builtin_amdgcn_exp2f)
  return __builtin_amdgcn_exp2f(x);
#else
  float r; asm("v_exp_f32 %0, %1" : "=v"(r) : "v"(x)); return r;
#endif
}
DEVINL void gload16(const void* g, void* l) {
  __builtin_amdgcn_global_load_lds(
      (const __attribute__((address_space(1))) unsigned*)g,
      (__attribute__((address_space(3))) unsigned*)l, 16, 0, 0);
}

// ---------------- fp32 -> bf16 weight convert ----------------
__global__ __launch_bounds__(256) void k_cvt(const float* __restrict__ s,
                                             unsigned short* __restrict__ d, int n4) {
  int i = blockIdx.x * 256 + threadIdx.x;
  if (i >= n4) return;
  float4v v = *(const float4v*)(s + (size_t)i * 4);
  ushort4v o;
  o[0] = f2bf(v[0]); o[1] = f2bf(v[1]); o[2] = f2bf(v[2]); o[3] = f2bf(v[3]);
  *(ushort4v*)(d + (size_t)i * 4) = o;
}

// ---------------- GroupNorm + transpose -> xn_t[b][t][c] bf16 ----------------
__global__ __launch_bounds__(256) void k_gn(const float* __restrict__ x,
                                            const float* __restrict__ gw,
                                            const float* __restrict__ gb,
                                            unsigned short* __restrict__ xnt) {
  int g = blockIdx.x, b = blockIdx.y, tid = threadIdx.x;
  const float* xb = x + ((size_t)b * 768 + g * 24) * 1024;
  float s = 0.f, ss = 0.f;
  for (int i = tid; i < 6144; i += 256) {
    float4v v = *(const float4v*)(xb + (size_t)i * 4);
    s += v[0] + v[1] + v[2] + v[3];
    ss += v[0] * v[0] + v[1] * v[1] + v[2] * v[2] + v[3] * v[3];
  }
  #pragma unroll
  for (int o = 32; o > 0; o >>= 1) { s += __shfl_down(s, o); ss += __shfl_down(ss, o); }
  __shared__ float rs[4], rss[4], stat[2];
  int w = tid >> 6;
  if ((tid & 63) == 0) { rs[w] = s; rss[w] = ss; }
  __syncthreads();
  if (tid == 0) {
    float S = rs[0] + rs[1] + rs[2] + rs[3], SS = rss[0] + rss[1] + rss[2] + rss[3];
    float mean = S / 24576.f;
    float var = SS / 24576.f - mean * mean;
    stat[0] = mean; stat[1] = rsqrtf(fmaxf(var, 0.f) + 1e-5f);
  }
  __syncthreads();
  float mean = stat[0], rstd = stat[1];
  float wv[24], bv[24];
  #pragma unroll
  for (int c = 0; c < 24; ++c) { wv[c] = gw[g * 24 + c]; bv[c] = gb[g * 24 + c]; }
  for (int it = 0; it < 4; ++it) {
    int t = it * 256 + tid;
    ushort8v ov[3];
    #pragma unroll
    for (int c = 0; c < 24; ++c) {
      float v = xb[(size_t)c * 1024 + t];
      ov[c >> 3][c & 7] = f2bf((v - mean) * rstd * wv[c] + bv[c]);
    }
    ushort8v* dst = (ushort8v*)(xnt + ((size_t)(b * 1024 + t)) * 768 + g * 24);
    dst[0] = ov[0]; dst[1] = ov[1]; dst[2] = ov[2];
  }
}

// ---------------- encoder transpose -> enc_t[b][s][c] bf16 ----------------
__global__ __launch_bounds__(256) void k_enc_tr(const float* __restrict__ enc,
                                                unsigned short* __restrict__ et) {
  int ct = blockIdx.x * 64, st = blockIdx.y * 64, b = blockIdx.z, tid = threadIdx.x;
  __shared__ unsigned short L[64 * 72];
  #pragma unroll
  for (int it = 0; it < 4; ++it) {
    int idx = it * 256 + tid; int r = idx >> 4, ch = idx & 15;
    float4v v = *(const float4v*)(enc + ((size_t)(b * 768 + ct + r)) * 256 + st + ch * 4);
    ushort4v o;
    o[0] = f2bf(v[0]); o[1] = f2bf(v[1]); o[2] = f2bf(v[2]); o[3] = f2bf(v[3]);
    *(ushort4v*)&L[r * 72 + ch * 4] = o;
  }
  __syncthreads();
  #pragma unroll
  for (int it = 0; it < 2; ++it) {
    int idx = it * 256 + tid; int s = idx >> 3, ch = idx & 7;
    ushort8v o;
    #pragma unroll
    for (int j = 0; j < 8; ++j) o[j] = L[(ch * 8 + j) * 72 + s];
    *(ushort8v*)(et + ((size_t)(b * 256 + st + s)) * 768 + ct + ch * 8) = o;
  }
}

// ---------------- build vcat[bh][c][s] bf16 ----------------
__global__ __launch_bounds__(256) void k_vcat(const unsigned short* __restrict__ qkvt,
                                              const unsigned short* __restrict__ ekvt,
                                              unsigned short* __restrict__ vcat) {
  int s0 = blockIdx.x * 64, bh = blockIdx.y, b = bh / 12, h = bh % 12, tid = threadIdx.x;
  __shared__ unsigned short L[64 * 72];
  #pragma unroll
  for (int it = 0; it < 2; ++it) {
    int idx = it * 256 + tid; int s = idx >> 3, ch = idx & 7;
    int sg = s0 + s;
    const unsigned short* src = (sg < 256)
        ? ekvt + ((size_t)(b * 256 + sg)) * 1536 + h * 128 + 64 + ch * 8
        : qkvt + ((size_t)(b * 1024 + sg - 256)) * 2304 + h * 192 + 128 + ch * 8;
    *(ushort8v*)&L[s * 72 + ch * 8] = *(const ushort8v*)src;
  }
  __syncthreads();
  #pragma unroll
  for (int it = 0; it < 2; ++it) {
    int idx = it * 256 + tid; int c = idx >> 3, ch = idx & 7;
    ushort8v o;
    #pragma unroll
    for (int j = 0; j < 8; ++j) o[j] = L[(ch * 8 + j) * 72 + c];
    *(ushort8v*)(vcat + ((size_t)bh * 64 + c) * 1280 + s0 + ch * 8) = o;
  }
}

// ---------------- GEMM: C[M][N] = A[M][K] * B[N][K]^T, global_load_lds staging ----
// EPI 0: out bf16, bias[col]   EPI 1: out fp32, bias[row] + resid
template <int EPI>
__global__ __launch_bounds__(256) void k_gemm(const unsigned short* __restrict__ A,
                                              const unsigned short* __restrict__ B,
                                              const float* __restrict__ bias,
                                              const float* __restrict__ resid,
                                              void* __restrict__ outp,
                                              int N, int K,
                                              long sA, long sB, long sO, long sR) {
  int bz = blockIdx.z;
  int m0 = blockIdx.x * 128, n0 = blockIdx.y * 128;
  const unsigned short* Ab = A + (size_t)bz * sA + (size_t)m0 * K;
  const unsigned short* Bb = B + (size_t)bz * sB + (size_t)n0 * K;
  __shared__ unsigned short As[128 * 32], Bs[128 * 32];
  int tid = threadIdx.x, lane = tid & 63, w = tid >> 6;
  int ln = lane & 15, lg = lane >> 4;
  int wm = (w >> 1) * 64, wn = (w & 1) * 64;
  int sr = lane >> 2, sc = lane & 3;
  int rA0 = w * 16 + sr, rA1 = w * 16 + 64 + sr;
  // pre-swizzled global sources (slot XOR row&3) -> linear LDS, swizzled reads
  const unsigned short* ga0 = Ab + (size_t)rA0 * K + ((sc ^ (rA0 & 3)) * 8);
  const unsigned short* ga1 = Ab + (size_t)rA1 * K + ((sc ^ (rA1 & 3)) * 8);
  const unsigned short* gb0 = Bb + (size_t)rA0 * K + ((sc ^ (rA0 & 3)) * 8);
  const unsigned short* gb1 = Bb + (size_t)rA1 * K + ((sc ^ (rA1 & 3)) * 8);
  unsigned short* la0 = &As[(w * 16) * 32];
  unsigned short* la1 = &As[(w * 16 + 64) * 32];
  unsigned short* lb0 = &Bs[(w * 16) * 32];
  unsigned short* lb1 = &Bs[(w * 16 + 64) * 32];
  int swz = (lg ^ (ln & 3)) * 8;

  f32x4 acc[4][4];
  #pragma unroll
  for (int i = 0; i < 4; ++i)
    #pragma unroll
    for (int j = 0; j < 4; ++j) acc[i][j] = (f32x4){0.f, 0.f, 0.f, 0.f};

  for (int k0 = 0; k0 < K; k0 += 32) {
    gload16(ga0 + k0, la0);
    gload16(ga1 + k0, la1);
    gload16(gb0 + k0, lb0);
    gload16(gb1 + k0, lb1);
    __syncthreads();
    bf16x8 af[4], bfv[4];
    #pragma unroll
    for (int i = 0; i < 4; ++i) af[i] = *(const bf16x8*)&As[(wm + i * 16 + ln) * 32 + swz];
    #pragma unroll
    for (int i = 0; i < 4; ++i) bfv[i] = *(const bf16x8*)&Bs[(wn + i * 16 + ln) * 32 + swz];
    #pragma unroll
    for (int i = 0; i < 4; ++i)
      #pragma unroll
      for (int j = 0; j < 4; ++j)
        acc[i][j] = __builtin_amdgcn_mfma_f32_16x16x32_bf16(af[i], bfv[j], acc[i][j], 0, 0, 0);
    __syncthreads();
  }

  #pragma unroll
  for (int i = 0; i < 4; ++i) {
    #pragma unroll
    for (int j = 0; j < 4; ++j) {
      #pragma unroll
      for (int r = 0; r < 4; ++r) {
        int row = m0 + wm + i * 16 + lg * 4 + r;
        int col = n0 + wn + j * 16 + ln;
        float v = acc[i][j][r];
        if (EPI == 0) {
          v += bias[col];
          ((unsigned short*)outp)[(size_t)bz * sO + (size_t)row * N + col] = f2bf(v);
        } else {
          v += bias[row] + resid[(size_t)bz * sR + (size_t)row * N + col];
          ((float*)outp)[(size_t)bz * sO + (size_t)row * N + col] = v;
        }
      }
    }
  }
}

// ---------------- flash attention: Q-tile 128, S-tile 64, 8 waves ----------------
// double-buffered K/V, async reg-staging, 1 barrier/tile, exp2 softmax, defer-max
__global__ __launch_bounds__(512) void k_attn(const unsigned short* __restrict__ qkvt,
                                              const unsigned short* __restrict__ ekvt,
                                              const unsigned short* __restrict__ vcat,
                                              unsigned short* __restrict__ at) {
  int bid = blockIdx.x;
  int swb = (bid & 7) * 96 + (bid >> 3);  // XCD-contiguous: all 8 t-tiles of a head on one XCD
  int t0 = (swb & 7) * 128, bh = swb >> 3, b = bh / 12, h = bh % 12;
  int tid = threadIdx.x, w = tid >> 6, lane = tid & 63, ln = lane & 15, lg = lane >> 4;
  __shared__ unsigned short Ks[2][64 * 68], Vs[2][64 * 68], Ps[128 * 68];

  const float QSC = 0.125f * 1.44269504089f;  // fold score scale + log2(e) into Q
  const unsigned short* qb = qkvt + ((size_t)(b * 1024 + t0 + w * 16 + ln)) * 2304 + h * 192;
  bf16x8 aq[2];
  #pragma unroll
  for (int kk = 0; kk < 2; ++kk) {
    bf16x8 q = *(const bf16x8*)(qb + kk * 32 + lg * 8);
    #pragma unroll
    for (int e = 0; e < 8; ++e) q[e] = (short)f2bf(bf2f((unsigned short)q[e]) * QSC);
    aq[kk] = q;
  }

  int sS = tid >> 3, sCh = tid & 7;
  int sB = sS * 68 + sCh * 8;
  const unsigned short* vsrc = vcat + ((size_t)bh * 64 + sS) * 1280 + sCh * 8;
  const unsigned short* ke_base = ekvt + ((size_t)(b * 256 + sS)) * 1536 + h * 128 + sCh * 8;
  const unsigned short* kq_base = qkvt + ((size_t)(b * 1024 + sS - 256)) * 2304 + h * 192 + 64 + sCh * 8;

  // prologue: stage tile 0
  {
    ushort8v k0v = *(const ushort8v*)ke_base;  // tile 0 is encoder region (sS<64<256)
    ushort8v v0v = *(const ushort8v*)vsrc;
    *(ushort8v*)&Ks[0][sB] = k0v;
    *(ushort8v*)&Vs[0][sB] = v0v;
  }
  __syncthreads();

  float m[4], l[4];
  f32x4 acc[4];
  #pragma unroll
  for (int r = 0; r < 4; ++r) { m[r] = -1e30f; l[r] = 0.f; }
  #pragma unroll
  for (int c = 0; c < 4; ++c) acc[c] = (f32x4){0.f, 0.f, 0.f, 0.f};

  ushort8v kreg, vreg;
  for (int t = 0; t < 20; ++t) {
    int cur = t & 1, nxt = cur ^ 1;
    if (t < 19) {  // issue next-tile loads early (T14): latency hides under compute
      int sg = (t + 1) * 64 + sS;
      kreg = (sg < 256) ? *(const ushort8v*)(ke_base + (size_t)(t + 1) * 64 * 1536)
                        : *(const ushort8v*)(kq_base + (size_t)(t + 1) * 64 * 2304);
      vreg = *(const ushort8v*)(vsrc + (t + 1) * 64);
    }
    // QK^T
    f32x4 sf[4];
    #pragma unroll
    for (int j = 0; j < 4; ++j) sf[j] = (f32x4){0.f, 0.f, 0.f, 0.f};
    #pragma unroll
    for (int kk = 0; kk < 2; ++kk)
      #pragma unroll
      for (int j = 0; j < 4; ++j) {
        bf16x8 bk = *(const bf16x8*)&Ks[cur][(j * 16 + ln) * 68 + kk * 32 + lg * 8];
        sf[j] = __builtin_amdgcn_mfma_f32_16x16x32_bf16(aq[kk], bk, sf[j], 0, 0, 0);
      }
    // row max (exp2 domain already)
    float mt[4];
    #pragma unroll
    for (int r = 0; r < 4; ++r) {
      float a = fmaxf(fmaxf(sf[0][r], sf[1][r]), fmaxf(sf[2][r], sf[3][r]));
      a = fmaxf(a, __shfl_xor(a, 1));
      a = fmaxf(a, __shfl_xor(a, 2));
      a = fmaxf(a, __shfl_xor(a, 4));
      a = fmaxf(a, __shfl_xor(a, 8));
      mt[r] = a;
    }
    bool nor = (mt[0] <= m[0] + 8.f) & (mt[1] <= m[1] + 8.f) &
               (mt[2] <= m[2] + 8.f) & (mt[3] <= m[3] + 8.f);
    if (!__all(nor)) {  // rescale (rare after tile 0)
      #pragma unroll
      for (int r = 0; r < 4; ++r) {
        float mn = fmaxf(m[r], mt[r]);
        float al = exp2a(m[r] - mn);
        m[r] = mn; l[r] *= al;
        #pragma unroll
        for (int c = 0; c < 4; ++c) acc[c][r] *= al;
      }
    }
    int prow = (w * 16 + lg * 4) * 68 + ln;
    #pragma unroll
    for (int r = 0; r < 4; ++r) {
      float rsum = 0.f;
      #pragma unroll
      for (int j = 0; j < 4; ++j) {
        float p = exp2a(sf[j][r] - m[r]);
        rsum += p;
        Ps[prow + r * 68 + j * 16] = f2bfr(p);
      }
      rsum += __shfl_xor(rsum, 1);
      rsum += __shfl_xor(rsum, 2);
      rsum += __shfl_xor(rsum, 4);
      rsum += __shfl_xor(rsum, 8);
      l[r] += rsum;
    }
    // PV (Ps is wave-private: same-wave DS ordering suffices, no barrier)
    #pragma unroll
    for (int ks = 0; ks < 2; ++ks) {
      bf16x8 ap = *(const bf16x8*)&Ps[(w * 16 + ln) * 68 + ks * 32 + lg * 8];
      #pragma unroll
      for (int c = 0; c < 4; ++c) {
        bf16x8 bv = *(const bf16x8*)&Vs[cur][(c * 16 + ln) * 68 + ks * 32 + lg * 8];
        acc[c] = __builtin_amdgcn_mfma_f32_16x16x32_bf16(ap, bv, acc[c], 0, 0, 0);
      }
    }
    if (t < 19) {  // write next tile (safe: buf nxt last read at tile t-1, barrier passed)
      *(ushort8v*)&Ks[nxt][sB] = kreg;
      *(ushort8v*)&Vs[nxt][sB] = vreg;
    }
    __syncthreads();
  }

  #pragma unroll
  for (int r = 0; r < 4; ++r) {
    float rl = 1.f / l[r];
    #pragma unroll
    for (int c = 0; c < 4; ++c) {
      at[((size_t)(b * 1024 + t0 + w * 16 + lg * 4 + r)) * 768 + h * 64 + c * 16 + ln] =
          f2bf(acc[c][r] * rl);
    }
  }
}

// ---------------- launch ----------------
extern "C" void kernel_launch(void* const* d_in, const int* in_sizes, int n_in,
                              void* d_out, int out_size, void* d_ws, size_t ws_size,
                              hipStream_t stream) {
  const float* x      = (const float*)d_in[0];
  const float* enc    = (const float*)d_in[1];
  const float* gn_w   = (const float*)d_in[2];
  const float* gn_b   = (const float*)d_in[3];
  const float* qkv_w  = (const float*)d_in[4];
  const float* qkv_b  = (const float*)d_in[5];
  const float* enc_w  = (const float*)d_in[6];
  const float* enc_b  = (const float*)d_in[7];
  const float* proj_w = (const float*)d_in[8];
  const float* proj_b = (const float*)d_in[9];
  float* out = (float*)d_out;

  char* ws = (char*)d_ws;
  unsigned short* w_qkv = (unsigned short*)(ws + 0);
  unsigned short* w_enc = (unsigned short*)(ws + 3538944);
  unsigned short* w_prj = (unsigned short*)(ws + 5898240);
  unsigned short* xn_t  = (unsigned short*)(ws + 7077888);
  unsigned short* enc_t = (unsigned short*)(ws + 19660800);
  unsigned short* qkv_t = (unsigned short*)(ws + 22806528);
  unsigned short* ekv_t = (unsigned short*)(ws + 60555264);
  unsigned short* vcat  = (unsigned short*)(ws + 66846720);
  unsigned short* a_t   = xn_t;

  k_cvt<<<1728, 256, 0, stream>>>(qkv_w, w_qkv, 442368);
  k_cvt<<<1152, 256, 0, stream>>>(enc_w, w_enc, 294912);
  k_cvt<<<576, 256, 0, stream>>>(proj_w, w_prj, 147456);
  k_gn<<<dim3(32, 8), 256, 0, stream>>>(x, gn_w, gn_b, xn_t);
  k_enc_tr<<<dim3(12, 4, 8), 256, 0, stream>>>(enc, enc_t);
  k_gemm<0><<<dim3(8, 18, 8), 256, 0, stream>>>(xn_t, w_qkv, qkv_b, nullptr, qkv_t,
                                                2304, 768, 786432L, 0L, 2359296L, 0L);
  k_gemm<0><<<dim3(2, 12, 8), 256, 0, stream>>>(enc_t, w_enc, enc_b, nullptr, ekv_t,
                                                1536, 768, 196608L, 0L, 393216L, 0L);
  k_vcat<<<dim3(20, 96), 256, 0, stream>>>(qkv_t, ekv_t, vcat);
  k_attn<<<dim3(768), 512, 0, stream>>>(qkv_t, ekv_t, vcat, a_t);
  k_gemm<1><<<dim3(6, 8, 8), 256, 0, stream>>>(w_prj, a_t, proj_b, x, out,
                                               1024, 768, 0L, 786432L, 786432L, 786432L);
}

// Round 3
// 193.392 us; speedup vs baseline: 1.2975x; 1.2442x over previous
//
#include <hip/hip_runtime.h>

typedef __attribute__((ext_vector_type(8))) short bf16x8;
typedef __attribute__((ext_vector_type(4))) float f32x4;
typedef __attribute__((ext_vector_type(16))) float f32x16;
typedef __attribute__((ext_vector_type(4))) float float4v;
typedef __attribute__((ext_vector_type(4))) unsigned short ushort4v;
typedef __attribute__((ext_vector_type(8))) unsigned short ushort8v;

#define DEVINL __device__ __forceinline__

// B=8, C=768, T=1024, heads=12, ch=64, EC=768, S_enc=256, S_tot=1280, groups=32

DEVINL unsigned short f2bf(float f) {
  union { float f; unsigned u; } v; v.f = f;
  unsigned r = (v.u + 0x7fffu + ((v.u >> 16) & 1u)) >> 16;  // RNE
  return (unsigned short)r;
}
DEVINL unsigned short f2bfr(float f) {  // cheap round
  union { float f; unsigned u; } v; v.f = f;
  return (unsigned short)((v.u + 0x8000u) >> 16);
}
DEVINL float bf2f(unsigned short h) {
  union { unsigned u; float f; } v; v.u = ((unsigned)h) << 16;
  return v.f;
}
DEVINL float exp2a(float x) {
#if __has_builtin(__builtin_amdgcn_exp2f)
  return __builtin_amdgcn_exp2f(x);
#else
  float r; asm("v_exp_f32 %0, %1" : "=v"(r) : "v"(x)); return r;
#endif
}
DEVINL void gload16(const void* g, void* l) {
  __builtin_amdgcn_global_load_lds(
      (const __attribute__((address_space(1))) unsigned*)g,
      (__attribute__((address_space(3))) unsigned*)l, 16, 0, 0);
}
DEVINL bf16x8 mkfrag(unsigned a, unsigned b, unsigned c, unsigned d) {
  union { unsigned u[4]; bf16x8 v; } x;
  x.u[0] = a; x.u[1] = b; x.u[2] = c; x.u[3] = d;
  return x.v;
}

// ---------------- fp32 -> bf16 weight convert ----------------
__global__ __launch_bounds__(256) void k_cvt(const float* __restrict__ s,
                                             unsigned short* __restrict__ d, int n4) {
  int i = blockIdx.x * 256 + threadIdx.x;
  if (i >= n4) return;
  float4v v = *(const float4v*)(s + (size_t)i * 4);
  ushort4v o;
  o[0] = f2bf(v[0]); o[1] = f2bf(v[1]); o[2] = f2bf(v[2]); o[3] = f2bf(v[3]);
  *(ushort4v*)(d + (size_t)i * 4) = o;
}

// ---------------- GroupNorm + transpose -> xn_t[b][t][c] bf16 ----------------
__global__ __launch_bounds__(256) void k_gn(const float* __restrict__ x,
                                            const float* __restrict__ gw,
                                            const float* __restrict__ gb,
                                            unsigned short* __restrict__ xnt) {
  int g = blockIdx.x, b = blockIdx.y, tid = threadIdx.x;
  const float* xb = x + ((size_t)b * 768 + g * 24) * 1024;
  float s = 0.f, ss = 0.f;
  for (int i = tid; i < 6144; i += 256) {
    float4v v = *(const float4v*)(xb + (size_t)i * 4);
    s += v[0] + v[1] + v[2] + v[3];
    ss += v[0] * v[0] + v[1] * v[1] + v[2] * v[2] + v[3] * v[3];
  }
  #pragma unroll
  for (int o = 32; o > 0; o >>= 1) { s += __shfl_down(s, o); ss += __shfl_down(ss, o); }
  __shared__ float rs[4], rss[4], stat[2];
  int w = tid >> 6;
  if ((tid & 63) == 0) { rs[w] = s; rss[w] = ss; }
  __syncthreads();
  if (tid == 0) {
    float S = rs[0] + rs[1] + rs[2] + rs[3], SS = rss[0] + rss[1] + rss[2] + rss[3];
    float mean = S / 24576.f;
    float var = SS / 24576.f - mean * mean;
    stat[0] = mean; stat[1] = rsqrtf(fmaxf(var, 0.f) + 1e-5f);
  }
  __syncthreads();
  float mean = stat[0], rstd = stat[1];
  float wv[24], bv[24];
  #pragma unroll
  for (int c = 0; c < 24; ++c) { wv[c] = gw[g * 24 + c]; bv[c] = gb[g * 24 + c]; }
  for (int it = 0; it < 4; ++it) {
    int t = it * 256 + tid;
    ushort8v ov[3];
    #pragma unroll
    for (int c = 0; c < 24; ++c) {
      float v = xb[(size_t)c * 1024 + t];
      ov[c >> 3][c & 7] = f2bf((v - mean) * rstd * wv[c] + bv[c]);
    }
    ushort8v* dst = (ushort8v*)(xnt + ((size_t)(b * 1024 + t)) * 768 + g * 24);
    dst[0] = ov[0]; dst[1] = ov[1]; dst[2] = ov[2];
  }
}

// ---------------- encoder transpose -> enc_t[b][s][c] bf16 ----------------
__global__ __launch_bounds__(256) void k_enc_tr(const float* __restrict__ enc,
                                                unsigned short* __restrict__ et) {
  int ct = blockIdx.x * 64, st = blockIdx.y * 64, b = blockIdx.z, tid = threadIdx.x;
  __shared__ unsigned short L[64 * 72];
  #pragma unroll
  for (int it = 0; it < 4; ++it) {
    int idx = it * 256 + tid; int r = idx >> 4, ch = idx & 15;
    float4v v = *(const float4v*)(enc + ((size_t)(b * 768 + ct + r)) * 256 + st + ch * 4);
    ushort4v o;
    o[0] = f2bf(v[0]); o[1] = f2bf(v[1]); o[2] = f2bf(v[2]); o[3] = f2bf(v[3]);
    *(ushort4v*)&L[r * 72 + ch * 4] = o;
  }
  __syncthreads();
  #pragma unroll
  for (int it = 0; it < 2; ++it) {
    int idx = it * 256 + tid; int s = idx >> 3, ch = idx & 7;
    ushort8v o;
    #pragma unroll
    for (int j = 0; j < 8; ++j) o[j] = L[(ch * 8 + j) * 72 + s];
    *(ushort8v*)(et + ((size_t)(b * 256 + st + s)) * 768 + ct + ch * 8) = o;
  }
}

// ---------------- build vcat[bh][c][s] bf16 ----------------
__global__ __launch_bounds__(256) void k_vcat(const unsigned short* __restrict__ qkvt,
                                              const unsigned short* __restrict__ ekvt,
                                              unsigned short* __restrict__ vcat) {
  int s0 = blockIdx.x * 64, bh = blockIdx.y, b = bh / 12, h = bh % 12, tid = threadIdx.x;
  __shared__ unsigned short L[64 * 72];
  #pragma unroll
  for (int it = 0; it < 2; ++it) {
    int idx = it * 256 + tid; int s = idx >> 3, ch = idx & 7;
    int sg = s0 + s;
    const unsigned short* src = (sg < 256)
        ? ekvt + ((size_t)(b * 256 + sg)) * 1536 + h * 128 + 64 + ch * 8
        : qkvt + ((size_t)(b * 1024 + sg - 256)) * 2304 + h * 192 + 128 + ch * 8;
    *(ushort8v*)&L[s * 72 + ch * 8] = *(const ushort8v*)src;
  }
  __syncthreads();
  #pragma unroll
  for (int it = 0; it < 2; ++it) {
    int idx = it * 256 + tid; int c = idx >> 3, ch = idx & 7;
    ushort8v o;
    #pragma unroll
    for (int j = 0; j < 8; ++j) o[j] = L[(ch * 8 + j) * 72 + c];
    *(ushort8v*)(vcat + ((size_t)bh * 64 + c) * 1280 + s0 + ch * 8) = o;
  }
}

// ---------------- GEMM: C[M][N] = A[M][K] * B[N][K]^T, global_load_lds staging ----
template <int EPI>
__global__ __launch_bounds__(256) void k_gemm(const unsigned short* __restrict__ A,
                                              const unsigned short* __restrict__ B,
                                              const float* __restrict__ bias,
                                              const float* __restrict__ resid,
                                              void* __restrict__ outp,
                                              int N, int K,
                                              long sA, long sB, long sO, long sR) {
  int bz = blockIdx.z;
  int m0 = blockIdx.x * 128, n0 = blockIdx.y * 128;
  const unsigned short* Ab = A + (size_t)bz * sA + (size_t)m0 * K;
  const unsigned short* Bb = B + (size_t)bz * sB + (size_t)n0 * K;
  __shared__ unsigned short As[128 * 32], Bs[128 * 32];
  int tid = threadIdx.x, lane = tid & 63, w = tid >> 6;
  int ln = lane & 15, lg = lane >> 4;
  int wm = (w >> 1) * 64, wn = (w & 1) * 64;
  int sr = lane >> 2, sc = lane & 3;
  int rA0 = w * 16 + sr, rA1 = w * 16 + 64 + sr;
  const unsigned short* ga0 = Ab + (size_t)rA0 * K + ((sc ^ (rA0 & 3)) * 8);
  const unsigned short* ga1 = Ab + (size_t)rA1 * K + ((sc ^ (rA1 & 3)) * 8);
  const unsigned short* gb0 = Bb + (size_t)rA0 * K + ((sc ^ (rA0 & 3)) * 8);
  const unsigned short* gb1 = Bb + (size_t)rA1 * K + ((sc ^ (rA1 & 3)) * 8);
  unsigned short* la0 = &As[(w * 16) * 32];
  unsigned short* la1 = &As[(w * 16 + 64) * 32];
  unsigned short* lb0 = &Bs[(w * 16) * 32];
  unsigned short* lb1 = &Bs[(w * 16 + 64) * 32];
  int swz = (lg ^ (ln & 3)) * 8;

  f32x4 acc[4][4];
  #pragma unroll
  for (int i = 0; i < 4; ++i)
    #pragma unroll
    for (int j = 0; j < 4; ++j) acc[i][j] = (f32x4){0.f, 0.f, 0.f, 0.f};

  for (int k0 = 0; k0 < K; k0 += 32) {
    gload16(ga0 + k0, la0);
    gload16(ga1 + k0, la1);
    gload16(gb0 + k0, lb0);
    gload16(gb1 + k0, lb1);
    __syncthreads();
    bf16x8 af[4], bfv[4];
    #pragma unroll
    for (int i = 0; i < 4; ++i) af[i] = *(const bf16x8*)&As[(wm + i * 16 + ln) * 32 + swz];
    #pragma unroll
    for (int i = 0; i < 4; ++i) bfv[i] = *(const bf16x8*)&Bs[(wn + i * 16 + ln) * 32 + swz];
    #pragma unroll
    for (int i = 0; i < 4; ++i)
      #pragma unroll
      for (int j = 0; j < 4; ++j)
        acc[i][j] = __builtin_amdgcn_mfma_f32_16x16x32_bf16(af[i], bfv[j], acc[i][j], 0, 0, 0);
    __syncthreads();
  }

  #pragma unroll
  for (int i = 0; i < 4; ++i) {
    #pragma unroll
    for (int j = 0; j < 4; ++j) {
      #pragma unroll
      for (int r = 0; r < 4; ++r) {
        int row = m0 + wm + i * 16 + lg * 4 + r;
        int col = n0 + wn + j * 16 + ln;
        float v = acc[i][j][r];
        if (EPI == 0) {
          v += bias[col];
          ((unsigned short*)outp)[(size_t)bz * sO + (size_t)row * N + col] = f2bf(v);
        } else {
          v += bias[row] + resid[(size_t)bz * sR + (size_t)row * N + col];
          ((float*)outp)[(size_t)bz * sO + (size_t)row * N + col] = v;
        }
      }
    }
  }
}

// ---------------- attention, m214-style: swapped QK, in-register softmax ----------
// 4 warps x QBLK=32, KVBLK=64, 32x32x16 MFMA. P^T[s][q]: lane q=lane&31 owns a row.
__global__ __launch_bounds__(256, 3) void k_attn(const unsigned short* __restrict__ qkvt,
                                                 const unsigned short* __restrict__ ekvt,
                                                 const unsigned short* __restrict__ vcat,
                                                 unsigned short* __restrict__ at) {
  int bid = blockIdx.x;
  int swb = (bid & 7) * 96 + (bid >> 3);  // XCD-contiguous head groups
  int t0 = (swb & 7) * 128, bh = swb >> 3, b = bh / 12, h = bh % 12;
  int tid = threadIdx.x, w = tid >> 6, lane = tid & 63;
  int ql = lane & 31, hi = lane >> 5;
  __shared__ unsigned short Ks[2][64 * 64], Vs[2][64 * 64];  // 32 KB total

  const float QSC = 0.125f * 1.44269504089f;  // score scale * log2(e), folded into Q
  // Q fragments (B-operand): j=q=lane&31, k-chunk jc: c = jc*16 + hi*8 + e
  bf16x8 aq[4];
  const unsigned short* qrow = qkvt + ((size_t)(b * 1024 + t0 + w * 32 + ql)) * 2304 + h * 192;
  #pragma unroll
  for (int jc = 0; jc < 4; ++jc) {
    ushort8v qv = *(const ushort8v*)(qrow + jc * 16 + hi * 8);
    bf16x8 o;
    #pragma unroll
    for (int e = 0; e < 8; ++e) o[e] = (short)f2bf(bf2f(qv[e]) * QSC);
    aq[jc] = o;
  }

  // staging: 256 threads, 2x16B each for K and V (64 rows x 128 B per tile)
  int r0 = tid >> 3, r1 = r0 + 32, ch16 = (tid & 7) * 16;
  int wr0 = r0 * 128 + (ch16 ^ ((r0 & 7) << 4));
  int wr1 = r1 * 128 + (ch16 ^ ((r0 & 7) << 4));  // (r0+32)&7 == r0&7
  const unsigned short* ke = ekvt + ((size_t)b * 256) * 1536 + h * 128 + (tid & 7) * 8;
  const unsigned short* kq = qkvt + ((long)(b * 1024) - 256) * 2304 + h * 192 + 64 + (tid & 7) * 8;
  const unsigned short* vb = vcat + ((size_t)bh * 64) * 1280 + (tid & 7) * 8;

  // prologue: tile 0 (encoder region)
  {
    ushort8v k0 = *(const ushort8v*)(ke + (size_t)r0 * 1536);
    ushort8v k1 = *(const ushort8v*)(ke + (size_t)r1 * 1536);
    ushort8v v0 = *(const ushort8v*)(vb + (size_t)r0 * 1280);
    ushort8v v1 = *(const ushort8v*)(vb + (size_t)r1 * 1280);
    *(ushort8v*)((char*)&Ks[0][0] + wr0) = k0;
    *(ushort8v*)((char*)&Ks[0][0] + wr1) = k1;
    *(ushort8v*)((char*)&Vs[0][0] + wr0) = v0;
    *(ushort8v*)((char*)&Vs[0][0] + wr1) = v1;
  }
  __syncthreads();

  f32x16 acc0, acc1;
  #pragma unroll
  for (int r = 0; r < 16; ++r) { acc0[r] = 0.f; acc1[r] = 0.f; }
  float m = -1e30f, l = 0.f;
  int xp = (ql & 7) << 4;  // read-side XOR swizzle

  for (int t = 0; t < 20; ++t) {
    int cur = t & 1, nxt = cur ^ 1;
    ushort8v kr0, kr1, vr0, vr1;
    if (t < 19) {  // T14: issue next-tile loads early
      int sg0 = (t + 1) * 64 + r0, sg1 = sg0 + 32;
      kr0 = (t + 1 < 4) ? *(const ushort8v*)(ke + (size_t)sg0 * 1536)
                        : *(const ushort8v*)(kq + (size_t)sg0 * 2304);
      kr1 = (t + 1 < 4) ? *(const ushort8v*)(ke + (size_t)sg1 * 1536)
                        : *(const ushort8v*)(kq + (size_t)sg1 * 2304);
      vr0 = *(const ushort8v*)(vb + (size_t)r0 * 1280 + (t + 1) * 64);
      vr1 = *(const ushort8v*)(vb + (size_t)r1 * 1280 + (t + 1) * 64);
    }
    // QK^T (swapped): sf[sb] = P^T[s 32sb..+31][q], accumulate over c
    f32x16 sf0, sf1;
    #pragma unroll
    for (int r = 0; r < 16; ++r) { sf0[r] = 0.f; sf1[r] = 0.f; }
    const char* kbase = (const char*)&Ks[cur][0] + ql * 128;
    __builtin_amdgcn_s_setprio(1);
    #pragma unroll
    for (int jc = 0; jc < 4; ++jc) {
      int off = (jc * 32 + hi * 16) ^ xp;
      bf16x8 k0f = *(const bf16x8*)(kbase + off);
      bf16x8 k1f = *(const bf16x8*)(kbase + 4096 + off);
      sf0 = __builtin_amdgcn_mfma_f32_32x32x16_bf16(k0f, aq[jc], sf0, 0, 0, 0);
      sf1 = __builtin_amdgcn_mfma_f32_32x32x16_bf16(k1f, aq[jc], sf1, 0, 0, 0);
    }
    __builtin_amdgcn_s_setprio(0);

    // row max over all 64 s (in-lane tree + one cross-half exchange)
    float mx[8];
    #pragma unroll
    for (int i = 0; i < 8; ++i)
      mx[i] = fmaxf(fmaxf(sf0[i], sf0[i + 8]), fmaxf(sf1[i], sf1[i + 8]));
    #pragma unroll
    for (int o = 4; o > 0; o >>= 1)
      #pragma unroll
      for (int i = 0; i < 4; ++i)
        if (i < o) mx[i] = fmaxf(mx[i], mx[i + o]);
    float mt = fmaxf(mx[0], __shfl_xor(mx[0], 32));
    if (!__all(mt <= m + 8.f)) {  // defer-max (T13)
      float mn = fmaxf(m, mt);
      float al = exp2a(m - mn);
      l *= al;
      #pragma unroll
      for (int r = 0; r < 16; ++r) { acc0[r] *= al; acc1[r] *= al; }
      m = mn;
    }

    const char* vbase = (const char*)&Vs[cur][0] + ql * 128;
    // per s-block: exp, pack, cross-half exchange -> PV B-frags, then PV MFMA
    #pragma unroll
    for (int sb = 0; sb < 2; ++sb) {
      unsigned pk[8];
      #pragma unroll
      for (int i = 0; i < 8; ++i) {
        float pa = exp2a((sb ? sf1[2 * i] : sf0[2 * i]) - m);
        float pb = exp2a((sb ? sf1[2 * i + 1] : sf0[2 * i + 1]) - m);
        l += pa + pb;
        pk[i] = (unsigned)f2bfr(pa) | ((unsigned)f2bfr(pb) << 16);
      }
      unsigned E1 = __shfl_xor(hi ? pk[0] : pk[2], 32);
      unsigned E2 = __shfl_xor(hi ? pk[1] : pk[3], 32);
      unsigned E3 = __shfl_xor(hi ? pk[4] : pk[6], 32);
      unsigned E4 = __shfl_xor(hi ? pk[5] : pk[7], 32);
      bf16x8 fj0 = hi ? mkfrag(E1, E2, pk[2], pk[3]) : mkfrag(pk[0], pk[1], E1, E2);
      bf16x8 fj1 = hi ? mkfrag(E3, E4, pk[6], pk[7]) : mkfrag(pk[4], pk[5], E3, E4);
      __builtin_amdgcn_s_setprio(1);
      #pragma unroll
      for (int jj = 0; jj < 2; ++jj) {
        int off = (sb * 64 + jj * 32 + hi * 16) ^ xp;
        bf16x8 v0f = *(const bf16x8*)(vbase + off);
        bf16x8 v1f = *(const bf16x8*)(vbase + 4096 + off);
        bf16x8 pf = jj ? fj1 : fj0;
        acc0 = __builtin_amdgcn_mfma_f32_32x32x16_bf16(v0f, pf, acc0, 0, 0, 0);
        acc1 = __builtin_amdgcn_mfma_f32_32x32x16_bf16(v1f, pf, acc1, 0, 0, 0);
      }
      __builtin_amdgcn_s_setprio(0);
    }

    if (t < 19) {  // write next tile, then single barrier
      *(ushort8v*)((char*)&Ks[nxt][0] + wr0) = kr0;
      *(ushort8v*)((char*)&Ks[nxt][0] + wr1) = kr1;
      *(ushort8v*)((char*)&Vs[nxt][0] + wr0) = vr0;
      *(ushort8v*)((char*)&Vs[nxt][0] + wr1) = vr1;
    }
    __syncthreads();
  }

  // epilogue: combine partner l, normalize, write O^T[c][q] -> at[b][t=q][h*64+c]
  l += __shfl_xor(l, 32);
  float rl = 1.f / l;
  unsigned short* orow = at + ((size_t)(b * 1024 + t0 + w * 32 + ql)) * 768 + h * 64;
  #pragma unroll
  for (int cb = 0; cb < 2; ++cb) {
    #pragma unroll
    for (int g = 0; g < 4; ++g) {
      int c = cb * 32 + g * 8 + hi * 4;
      ushort4v o;
      #pragma unroll
      for (int i = 0; i < 4; ++i) {
        float v = (cb ? acc1[g * 4 + i] : acc0[g * 4 + i]) * rl;
        o[i] = f2bf(v);
      }
      *(ushort4v*)(orow + c) = o;
    }
  }
}

// ---------------- launch ----------------
extern "C" void kernel_launch(void* const* d_in, const int* in_sizes, int n_in,
                              void* d_out, int out_size, void* d_ws, size_t ws_size,
                              hipStream_t stream) {
  const float* x      = (const float*)d_in[0];
  const float* enc    = (const float*)d_in[1];
  const float* gn_w   = (const float*)d_in[2];
  const float* gn_b   = (const float*)d_in[3];
  const float* qkv_w  = (const float*)d_in[4];
  const float* qkv_b  = (const float*)d_in[5];
  const float* enc_w  = (const float*)d_in[6];
  const float* enc_b  = (const float*)d_in[7];
  const float* proj_w = (const float*)d_in[8];
  const float* proj_b = (const float*)d_in[9];
  float* out = (float*)d_out;

  char* ws = (char*)d_ws;
  unsigned short* w_qkv = (unsigned short*)(ws + 0);
  unsigned short* w_enc = (unsigned short*)(ws + 3538944);
  unsigned short* w_prj = (unsigned short*)(ws + 5898240);
  unsigned short* xn_t  = (unsigned short*)(ws + 7077888);
  unsigned short* enc_t = (unsigned short*)(ws + 19660800);
  unsigned short* qkv_t = (unsigned short*)(ws + 22806528);
  unsigned short* ekv_t = (unsigned short*)(ws + 60555264);
  unsigned short* vcat  = (unsigned short*)(ws + 66846720);
  unsigned short* a_t   = xn_t;

  k_cvt<<<1728, 256, 0, stream>>>(qkv_w, w_qkv, 442368);
  k_cvt<<<1152, 256, 0, stream>>>(enc_w, w_enc, 294912);
  k_cvt<<<576, 256, 0, stream>>>(proj_w, w_prj, 147456);
  k_gn<<<dim3(32, 8), 256, 0, stream>>>(x, gn_w, gn_b, xn_t);
  k_enc_tr<<<dim3(12, 4, 8), 256, 0, stream>>>(enc, enc_t);
  k_gemm<0><<<dim3(8, 18, 8), 256, 0, stream>>>(xn_t, w_qkv, qkv_b, nullptr, qkv_t,
                                                2304, 768, 786432L, 0L, 2359296L, 0L);
  k_gemm<0><<<dim3(2, 12, 8), 256, 0, stream>>>(enc_t, w_enc, enc_b, nullptr, ekv_t,
                                                1536, 768, 196608L, 0L, 393216L, 0L);
  k_vcat<<<dim3(20, 96), 256, 0, stream>>>(qkv_t, ekv_t, vcat);
  k_attn<<<dim3(768), 256, 0, stream>>>(qkv_t, ekv_t, vcat, a_t);
  k_gemm<1><<<dim3(6, 8, 8), 256, 0, stream>>>(w_prj, a_t, proj_b, x, out,
                                               1024, 768, 0L, 786432L, 786432L, 786432L);
}

// Round 4
// 192.588 us; speedup vs baseline: 1.3029x; 1.0042x over previous
//
#include <hip/hip_runtime.h>

typedef __attribute__((ext_vector_type(8))) short bf16x8;
typedef __attribute__((ext_vector_type(4))) float f32x4;
typedef __attribute__((ext_vector_type(16))) float f32x16;
typedef __attribute__((ext_vector_type(4))) float float4v;
typedef __attribute__((ext_vector_type(4))) unsigned short ushort4v;
typedef __attribute__((ext_vector_type(8))) unsigned short ushort8v;

#define DEVINL __device__ __forceinline__

// B=8, C=768, T=1024, heads=12, ch=64, EC=768, S_enc=256, S_tot=1280, groups=32

DEVINL unsigned short f2bf(float f) {
  union { float f; unsigned u; } v; v.f = f;
  unsigned r = (v.u + 0x7fffu + ((v.u >> 16) & 1u)) >> 16;  // RNE
  return (unsigned short)r;
}
DEVINL unsigned short f2bfr(float f) {  // cheap round
  union { float f; unsigned u; } v; v.f = f;
  return (unsigned short)((v.u + 0x8000u) >> 16);
}
DEVINL float bf2f(unsigned short h) {
  union { unsigned u; float f; } v; v.u = ((unsigned)h) << 16;
  return v.f;
}
DEVINL float exp2a(float x) {
#if __has_builtin(__builtin_amdgcn_exp2f)
  return __builtin_amdgcn_exp2f(x);
#else
  float r; asm("v_exp_f32 %0, %1" : "=v"(r) : "v"(x)); return r;
#endif
}
DEVINL void gload16(const void* g, void* l) {
  __builtin_amdgcn_global_load_lds(
      (const __attribute__((address_space(1))) unsigned*)g,
      (__attribute__((address_space(3))) unsigned*)l, 16, 0, 0);
}
DEVINL void plswap(unsigned& a, unsigned& b) {  // a'={a.lo,b.lo}, b'={a.hi,b.hi}
  asm("v_permlane32_swap_b32 %0, %1" : "+v"(a), "+v"(b));
}
DEVINL bf16x8 mkfrag(unsigned a, unsigned b, unsigned c, unsigned d) {
  union { unsigned u[4]; bf16x8 v; } x;
  x.u[0] = a; x.u[1] = b; x.u[2] = c; x.u[3] = d;
  return x.v;
}

// ---------------- fp32 -> bf16 weight convert ----------------
__global__ __launch_bounds__(256) void k_cvt(const float* __restrict__ s,
                                             unsigned short* __restrict__ d, int n4) {
  int i = blockIdx.x * 256 + threadIdx.x;
  if (i >= n4) return;
  float4v v = *(const float4v*)(s + (size_t)i * 4);
  ushort4v o;
  o[0] = f2bf(v[0]); o[1] = f2bf(v[1]); o[2] = f2bf(v[2]); o[3] = f2bf(v[3]);
  *(ushort4v*)(d + (size_t)i * 4) = o;
}

// ---------------- GroupNorm + transpose -> xn_t[b][t][c] bf16 ----------------
__global__ __launch_bounds__(256) void k_gn(const float* __restrict__ x,
                                            const float* __restrict__ gw,
                                            const float* __restrict__ gb,
                                            unsigned short* __restrict__ xnt) {
  int g = blockIdx.x, b = blockIdx.y, tid = threadIdx.x;
  const float* xb = x + ((size_t)b * 768 + g * 24) * 1024;
  float s = 0.f, ss = 0.f;
  for (int i = tid; i < 6144; i += 256) {
    float4v v = *(const float4v*)(xb + (size_t)i * 4);
    s += v[0] + v[1] + v[2] + v[3];
    ss += v[0] * v[0] + v[1] * v[1] + v[2] * v[2] + v[3] * v[3];
  }
  #pragma unroll
  for (int o = 32; o > 0; o >>= 1) { s += __shfl_down(s, o); ss += __shfl_down(ss, o); }
  __shared__ float rs[4], rss[4], stat[2];
  int w = tid >> 6;
  if ((tid & 63) == 0) { rs[w] = s; rss[w] = ss; }
  __syncthreads();
  if (tid == 0) {
    float S = rs[0] + rs[1] + rs[2] + rs[3], SS = rss[0] + rss[1] + rss[2] + rss[3];
    float mean = S / 24576.f;
    float var = SS / 24576.f - mean * mean;
    stat[0] = mean; stat[1] = rsqrtf(fmaxf(var, 0.f) + 1e-5f);
  }
  __syncthreads();
  float mean = stat[0], rstd = stat[1];
  float wv[24], bv[24];
  #pragma unroll
  for (int c = 0; c < 24; ++c) { wv[c] = gw[g * 24 + c]; bv[c] = gb[g * 24 + c]; }
  for (int it = 0; it < 4; ++it) {
    int t = it * 256 + tid;
    ushort8v ov[3];
    #pragma unroll
    for (int c = 0; c < 24; ++c) {
      float v = xb[(size_t)c * 1024 + t];
      ov[c >> 3][c & 7] = f2bf((v - mean) * rstd * wv[c] + bv[c]);
    }
    ushort8v* dst = (ushort8v*)(xnt + ((size_t)(b * 1024 + t)) * 768 + g * 24);
    dst[0] = ov[0]; dst[1] = ov[1]; dst[2] = ov[2];
  }
}

// ---------------- encoder transpose -> enc_t[b][s][c] bf16 ----------------
__global__ __launch_bounds__(256) void k_enc_tr(const float* __restrict__ enc,
                                                unsigned short* __restrict__ et) {
  int ct = blockIdx.x * 64, st = blockIdx.y * 64, b = blockIdx.z, tid = threadIdx.x;
  __shared__ unsigned short L[64 * 72];
  #pragma unroll
  for (int it = 0; it < 4; ++it) {
    int idx = it * 256 + tid; int r = idx >> 4, ch = idx & 15;
    float4v v = *(const float4v*)(enc + ((size_t)(b * 768 + ct + r)) * 256 + st + ch * 4);
    ushort4v o;
    o[0] = f2bf(v[0]); o[1] = f2bf(v[1]); o[2] = f2bf(v[2]); o[3] = f2bf(v[3]);
    *(ushort4v*)&L[r * 72 + ch * 4] = o;
  }
  __syncthreads();
  #pragma unroll
  for (int it = 0; it < 2; ++it) {
    int idx = it * 256 + tid; int s = idx >> 3, ch = idx & 7;
    ushort8v o;
    #pragma unroll
    for (int j = 0; j < 8; ++j) o[j] = L[(ch * 8 + j) * 72 + s];
    *(ushort8v*)(et + ((size_t)(b * 256 + st + s)) * 768 + ct + ch * 8) = o;
  }
}

// ---------------- build vcat[bh][c][s] bf16 ----------------
__global__ __launch_bounds__(256) void k_vcat(const unsigned short* __restrict__ qkvt,
                                              const unsigned short* __restrict__ ekvt,
                                              unsigned short* __restrict__ vcat) {
  int s0 = blockIdx.x * 64, bh = blockIdx.y, b = bh / 12, h = bh % 12, tid = threadIdx.x;
  __shared__ unsigned short L[64 * 72];
  #pragma unroll
  for (int it = 0; it < 2; ++it) {
    int idx = it * 256 + tid; int s = idx >> 3, ch = idx & 7;
    int sg = s0 + s;
    const unsigned short* src = (sg < 256)
        ? ekvt + ((size_t)(b * 256 + sg)) * 1536 + h * 128 + 64 + ch * 8
        : qkvt + ((size_t)(b * 1024 + sg - 256)) * 2304 + h * 192 + 128 + ch * 8;
    *(ushort8v*)&L[s * 72 + ch * 8] = *(const ushort8v*)src;
  }
  __syncthreads();
  #pragma unroll
  for (int it = 0; it < 2; ++it) {
    int idx = it * 256 + tid; int c = idx >> 3, ch = idx & 7;
    ushort8v o;
    #pragma unroll
    for (int j = 0; j < 8; ++j) o[j] = L[(ch * 8 + j) * 72 + c];
    *(ushort8v*)(vcat + ((size_t)bh * 64 + c) * 1280 + s0 + ch * 8) = o;
  }
}

// ---------------- GEMM: C[M][N] = A[M][K] * B[N][K]^T, global_load_lds staging ----
template <int EPI>
__global__ __launch_bounds__(256) void k_gemm(const unsigned short* __restrict__ A,
                                              const unsigned short* __restrict__ B,
                                              const float* __restrict__ bias,
                                              const float* __restrict__ resid,
                                              void* __restrict__ outp,
                                              int N, int K,
                                              long sA, long sB, long sO, long sR) {
  int bz = blockIdx.z;
  int m0 = blockIdx.x * 128, n0 = blockIdx.y * 128;
  const unsigned short* Ab = A + (size_t)bz * sA + (size_t)m0 * K;
  const unsigned short* Bb = B + (size_t)bz * sB + (size_t)n0 * K;
  __shared__ unsigned short As[128 * 32], Bs[128 * 32];
  int tid = threadIdx.x, lane = tid & 63, w = tid >> 6;
  int ln = lane & 15, lg = lane >> 4;
  int wm = (w >> 1) * 64, wn = (w & 1) * 64;
  int sr = lane >> 2, sc = lane & 3;
  int rA0 = w * 16 + sr, rA1 = w * 16 + 64 + sr;
  const unsigned short* ga0 = Ab + (size_t)rA0 * K + ((sc ^ (rA0 & 3)) * 8);
  const unsigned short* ga1 = Ab + (size_t)rA1 * K + ((sc ^ (rA1 & 3)) * 8);
  const unsigned short* gb0 = Bb + (size_t)rA0 * K + ((sc ^ (rA0 & 3)) * 8);
  const unsigned short* gb1 = Bb + (size_t)rA1 * K + ((sc ^ (rA1 & 3)) * 8);
  unsigned short* la0 = &As[(w * 16) * 32];
  unsigned short* la1 = &As[(w * 16 + 64) * 32];
  unsigned short* lb0 = &Bs[(w * 16) * 32];
  unsigned short* lb1 = &Bs[(w * 16 + 64) * 32];
  int swz = (lg ^ (ln & 3)) * 8;

  f32x4 acc[4][4];
  #pragma unroll
  for (int i = 0; i < 4; ++i)
    #pragma unroll
    for (int j = 0; j < 4; ++j) acc[i][j] = (f32x4){0.f, 0.f, 0.f, 0.f};

  for (int k0 = 0; k0 < K; k0 += 32) {
    gload16(ga0 + k0, la0);
    gload16(ga1 + k0, la1);
    gload16(gb0 + k0, lb0);
    gload16(gb1 + k0, lb1);
    __syncthreads();
    bf16x8 af[4], bfv[4];
    #pragma unroll
    for (int i = 0; i < 4; ++i) af[i] = *(const bf16x8*)&As[(wm + i * 16 + ln) * 32 + swz];
    #pragma unroll
    for (int i = 0; i < 4; ++i) bfv[i] = *(const bf16x8*)&Bs[(wn + i * 16 + ln) * 32 + swz];
    #pragma unroll
    for (int i = 0; i < 4; ++i)
      #pragma unroll
      for (int j = 0; j < 4; ++j)
        acc[i][j] = __builtin_amdgcn_mfma_f32_16x16x32_bf16(af[i], bfv[j], acc[i][j], 0, 0, 0);
    __syncthreads();
  }

  #pragma unroll
  for (int i = 0; i < 4; ++i) {
    #pragma unroll
    for (int j = 0; j < 4; ++j) {
      #pragma unroll
      for (int r = 0; r < 4; ++r) {
        int row = m0 + wm + i * 16 + lg * 4 + r;
        int col = n0 + wn + j * 16 + ln;
        float v = acc[i][j][r];
        if (EPI == 0) {
          v += bias[col];
          ((unsigned short*)outp)[(size_t)bz * sO + (size_t)row * N + col] = f2bf(v);
        } else {
          v += bias[row] + resid[(size_t)bz * sR + (size_t)row * N + col];
          ((float*)outp)[(size_t)bz * sO + (size_t)row * N + col] = v;
        }
      }
    }
  }
}

// ---------------- attention: swapped QK, in-reg softmax, gload_lds staging -------
// 4 warps x QBLK=32, KVBLK=64, 32x32x16 MFMA. Lane q=lane&31 owns a softmax row.
// K/V staged via global_load_lds (linear LDS, pre-swizzled global source);
// P redistributed with v_permlane32_swap (VALU pipe, zero DS ops).
__global__ __launch_bounds__(256, 3) void k_attn(const unsigned short* __restrict__ qkvt,
                                                 const unsigned short* __restrict__ ekvt,
                                                 const unsigned short* __restrict__ vcat,
                                                 unsigned short* __restrict__ at) {
  int bid = blockIdx.x;
  int swb = (bid & 7) * 96 + (bid >> 3);  // XCD-contiguous head groups
  int t0 = (swb & 7) * 128, bh = swb >> 3, b = bh / 12, h = bh % 12;
  int tid = threadIdx.x, w = tid >> 6, lane = tid & 63;
  int ql = lane & 31, hi = lane >> 5;
  __shared__ unsigned short Ks[2][4096], Vs[2][4096];  // 2 x 64 rows x 128 B, x2 dbuf

  const float QSC = 0.125f * 1.44269504089f;  // score scale * log2(e), folded into Q
  bf16x8 aq[4];
  const unsigned short* qrow = qkvt + ((size_t)(b * 1024 + t0 + w * 32 + ql)) * 2304 + h * 192;
  #pragma unroll
  for (int jc = 0; jc < 4; ++jc) {
    ushort8v qv = *(const ushort8v*)(qrow + jc * 16 + hi * 8);
    bf16x8 o;
    #pragma unroll
    for (int e = 0; e < 8; ++e) o[e] = (short)f2bf(bf2f(qv[e]) * QSC);
    aq[jc] = o;
  }

  // staging lane constants: wave w stages rows [w*16, w*16+16); per lane: rows
  // rloc, rloc+8, source column pre-swizzled so linear LDS holds XOR-swizzled data
  int rloc = w * 16 + (lane >> 3);
  int chunk = (lane & 7) ^ (lane >> 3);  // (rloc&7) == lane>>3
  const unsigned short* ke_st = ekvt + ((size_t)(b * 256 + rloc)) * 1536 + h * 128 + chunk * 8;
  const unsigned short* kq_st = qkvt + ((long)b * 1024 - 256 + rloc) * 2304 + h * 192 + 64 + chunk * 8;
  const unsigned short* v_st  = vcat + ((size_t)(bh * 64 + rloc)) * 1280 + chunk * 8;
  unsigned short* kd = &Ks[0][0] + w * 1024;  // wave-uniform LDS dest (1 KB/issue)
  unsigned short* vd = &Vs[0][0] + w * 1024;

  auto stage = [&](int nb, int tn) {
    const unsigned short* ks;
    size_t rstep;
    if (tn < 4) { ks = ke_st + (size_t)tn * 64 * 1536; rstep = 8 * 1536; }
    else        { ks = kq_st + (size_t)tn * 64 * 2304; rstep = 8 * 2304; }
    unsigned short* kdd = kd + nb * 4096;
    unsigned short* vdd = vd + nb * 4096;
    const unsigned short* vs = v_st + tn * 64;
    gload16(ks, kdd);
    gload16(ks + rstep, kdd + 512);
    gload16(vs, vdd);
    gload16(vs + 8 * 1280, vdd + 512);
  };

  stage(0, 0);
  asm volatile("s_waitcnt vmcnt(0)" ::: "memory");
  __syncthreads();

  f32x16 acc0, acc1;
  #pragma unroll
  for (int r = 0; r < 16; ++r) { acc0[r] = 0.f; acc1[r] = 0.f; }
  float m = -1e30f, l = 0.f;
  int xp = (ql & 7) << 4;  // read-side XOR swizzle (bytes)

  for (int t = 0; t < 20; ++t) {
    int cur = t & 1;
    if (t < 19) stage(cur ^ 1, t + 1);  // async: in flight across whole tile compute

    // QK^T (swapped): sf = P^T[s][q]
    f32x16 sf0, sf1;
    #pragma unroll
    for (int r = 0; r < 16; ++r) { sf0[r] = 0.f; sf1[r] = 0.f; }
    const char* kbase = (const char*)&Ks[cur][0] + ql * 128;
    __builtin_amdgcn_s_setprio(1);
    #pragma unroll
    for (int jc = 0; jc < 4; ++jc) {
      int off = (jc * 32 + hi * 16) ^ xp;
      bf16x8 k0f = *(const bf16x8*)(kbase + off);
      bf16x8 k1f = *(const bf16x8*)(kbase + 4096 + off);
      sf0 = __builtin_amdgcn_mfma_f32_32x32x16_bf16(k0f, aq[jc], sf0, 0, 0, 0);
      sf1 = __builtin_amdgcn_mfma_f32_32x32x16_bf16(k1f, aq[jc], sf1, 0, 0, 0);
    }
    __builtin_amdgcn_s_setprio(0);

    // row max over 64 s (in-lane tree + one cross-half exchange)
    float mx[8];
    #pragma unroll
    for (int i = 0; i < 8; ++i)
      mx[i] = fmaxf(fmaxf(sf0[i], sf0[i + 8]), fmaxf(sf1[i], sf1[i + 8]));
    #pragma unroll
    for (int o = 4; o > 0; o >>= 1)
      #pragma unroll
      for (int i = 0; i < 4; ++i)
        if (i < o) mx[i] = fmaxf(mx[i], mx[i + o]);
    float mt = fmaxf(mx[0], __shfl_xor(mx[0], 32));
    if (!__all(mt <= m + 8.f)) {  // defer-max (T13)
      float mn = fmaxf(m, mt);
      float al = exp2a(m - mn);
      l *= al;
      #pragma unroll
      for (int r = 0; r < 16; ++r) { acc0[r] *= al; acc1[r] *= al; }
      m = mn;
    }

    const char* vbase = (const char*)&Vs[cur][0] + ql * 128;
    #pragma unroll
    for (int sb = 0; sb < 2; ++sb) {
      unsigned pk[8];
      #pragma unroll
      for (int i = 0; i < 8; ++i) {
        float pa = exp2a((sb ? sf1[2 * i] : sf0[2 * i]) - m);
        float pb = exp2a((sb ? sf1[2 * i + 1] : sf0[2 * i + 1]) - m);
        l += pa + pb;
        pk[i] = (unsigned)f2bfr(pa) | ((unsigned)f2bfr(pb) << 16);
      }
      // permlane32_swap: pk0..3 -> words w0..w3 of fj0 (k=0..15), pk4..7 -> fj1
      plswap(pk[0], pk[2]);
      plswap(pk[1], pk[3]);
      plswap(pk[4], pk[6]);
      plswap(pk[5], pk[7]);
      bf16x8 fj0 = mkfrag(pk[0], pk[1], pk[2], pk[3]);
      bf16x8 fj1 = mkfrag(pk[4], pk[5], pk[6], pk[7]);
      __builtin_amdgcn_s_setprio(1);
      #pragma unroll
      for (int jj = 0; jj < 2; ++jj) {
        int off = (sb * 64 + jj * 32 + hi * 16) ^ xp;
        bf16x8 v0f = *(const bf16x8*)(vbase + off);
        bf16x8 v1f = *(const bf16x8*)(vbase + 4096 + off);
        bf16x8 pf = jj ? fj1 : fj0;
        acc0 = __builtin_amdgcn_mfma_f32_32x32x16_bf16(v0f, pf, acc0, 0, 0, 0);
        acc1 = __builtin_amdgcn_mfma_f32_32x32x16_bf16(v1f, pf, acc1, 0, 0, 0);
      }
      __builtin_amdgcn_s_setprio(0);
    }

    if (t < 19) asm volatile("s_waitcnt vmcnt(0)" ::: "memory");  // next tile staged
    __syncthreads();
  }

  // epilogue: combine partner l, normalize, write O -> at[b][t=q][h*64+c]
  l += __shfl_xor(l, 32);
  float rl = 1.f / l;
  unsigned short* orow = at + ((size_t)(b * 1024 + t0 + w * 32 + ql)) * 768 + h * 64;
  #pragma unroll
  for (int cb = 0; cb < 2; ++cb) {
    #pragma unroll
    for (int g = 0; g < 4; ++g) {
      int c = cb * 32 + g * 8 + hi * 4;
      ushort4v o;
      #pragma unroll
      for (int i = 0; i < 4; ++i) {
        float v = (cb ? acc1[g * 4 + i] : acc0[g * 4 + i]) * rl;
        o[i] = f2bf(v);
      }
      *(ushort4v*)(orow + c) = o;
    }
  }
}

// ---------------- launch ----------------
extern "C" void kernel_launch(void* const* d_in, const int* in_sizes, int n_in,
                              void* d_out, int out_size, void* d_ws, size_t ws_size,
                              hipStream_t stream) {
  const float* x      = (const float*)d_in[0];
  const float* enc    = (const float*)d_in[1];
  const float* gn_w   = (const float*)d_in[2];
  const float* gn_b   = (const float*)d_in[3];
  const float* qkv_w  = (const float*)d_in[4];
  const float* qkv_b  = (const float*)d_in[5];
  const float* enc_w  = (const float*)d_in[6];
  const float* enc_b  = (const float*)d_in[7];
  const float* proj_w = (const float*)d_in[8];
  const float* proj_b = (const float*)d_in[9];
  float* out = (float*)d_out;

  char* ws = (char*)d_ws;
  unsigned short* w_qkv = (unsigned short*)(ws + 0);
  unsigned short* w_enc = (unsigned short*)(ws + 3538944);
  unsigned short* w_prj = (unsigned short*)(ws + 5898240);
  unsigned short* xn_t  = (unsigned short*)(ws + 7077888);
  unsigned short* enc_t = (unsigned short*)(ws + 19660800);
  unsigned short* qkv_t = (unsigned short*)(ws + 22806528);
  unsigned short* ekv_t = (unsigned short*)(ws + 60555264);
  unsigned short* vcat  = (unsigned short*)(ws + 66846720);
  unsigned short* a_t   = xn_t;

  k_cvt<<<1728, 256, 0, stream>>>(qkv_w, w_qkv, 442368);
  k_cvt<<<1152, 256, 0, stream>>>(enc_w, w_enc, 294912);
  k_cvt<<<576, 256, 0, stream>>>(proj_w, w_prj, 147456);
  k_gn<<<dim3(32, 8), 256, 0, stream>>>(x, gn_w, gn_b, xn_t);
  k_enc_tr<<<dim3(12, 4, 8), 256, 0, stream>>>(enc, enc_t);
  k_gemm<0><<<dim3(8, 18, 8), 256, 0, stream>>>(xn_t, w_qkv, qkv_b, nullptr, qkv_t,
                                                2304, 768, 786432L, 0L, 2359296L, 0L);
  k_gemm<0><<<dim3(2, 12, 8), 256, 0, stream>>>(enc_t, w_enc, enc_b, nullptr, ekv_t,
                                                1536, 768, 196608L, 0L, 393216L, 0L);
  k_vcat<<<dim3(20, 96), 256, 0, stream>>>(qkv_t, ekv_t, vcat);
  k_attn<<<dim3(768), 256, 0, stream>>>(qkv_t, ekv_t, vcat, a_t);
  k_gemm<1><<<dim3(6, 8, 8), 256, 0, stream>>>(w_prj, a_t, proj_b, x, out,
                                               1024, 768, 0L, 786432L, 786432L, 786432L);
}

// Round 5
// 173.368 us; speedup vs baseline: 1.4473x; 1.1109x over previous
//
#include <hip/hip_runtime.h>

typedef __attribute__((ext_vector_type(8))) short bf16x8;
typedef __attribute__((ext_vector_type(4))) float f32x4;
typedef __attribute__((ext_vector_type(16))) float f32x16;
typedef __attribute__((ext_vector_type(4))) float float4v;
typedef __attribute__((ext_vector_type(4))) unsigned short ushort4v;
typedef __attribute__((ext_vector_type(8))) unsigned short ushort8v;

#define DEVINL __device__ __forceinline__

// B=8, C=768, T=1024, heads=12, ch=64, EC=768, S_enc=256, S_tot=1280, groups=32

DEVINL unsigned short f2bf(float f) {
  union { float f; unsigned u; } v; v.f = f;
  unsigned r = (v.u + 0x7fffu + ((v.u >> 16) & 1u)) >> 16;  // RNE
  return (unsigned short)r;
}
DEVINL float bf2f(unsigned short h) {
  union { unsigned u; float f; } v; v.u = ((unsigned)h) << 16;
  return v.f;
}
DEVINL float exp2a(float x) {
  float r; asm("v_exp_f32 %0, %1" : "=v"(r) : "v"(x)); return r;
}
DEVINL unsigned cvtpk(float lo, float hi) {  // dst = bf16(lo) | bf16(hi)<<16, RNE
  unsigned r;
  asm("v_cvt_pk_bf16_f32 %0, %1, %2" : "=v"(r) : "v"(lo), "v"(hi));
  return r;
}
DEVINL void gload16(const void* g, void* l) {
  __builtin_amdgcn_global_load_lds(
      (const __attribute__((address_space(1))) unsigned*)g,
      (__attribute__((address_space(3))) unsigned*)l, 16, 0, 0);
}
DEVINL void plswap(unsigned& a, unsigned& b) {  // a'={a.lo,b.lo}, b'={a.hi,b.hi}
  asm("v_permlane32_swap_b32 %0, %1" : "+v"(a), "+v"(b));
}
DEVINL bf16x8 mkfrag(unsigned a, unsigned b, unsigned c, unsigned d) {
  union { unsigned u[4]; bf16x8 v; } x;
  x.u[0] = a; x.u[1] = b; x.u[2] = c; x.u[3] = d;
  return x.v;
}

// ---------------- fused fp32 -> bf16 weight convert (all 3 weights) ----------------
__global__ __launch_bounds__(256) void k_cvt3(const float* __restrict__ s0,
                                              const float* __restrict__ s1,
                                              const float* __restrict__ s2,
                                              unsigned short* __restrict__ d) {
  int i = blockIdx.x * 256 + threadIdx.x;  // 884736 float4s total
  const float* s; int off;
  if (i < 442368)      { s = s0; off = i; }
  else if (i < 737280) { s = s1; off = i - 442368; }
  else                 { s = s2; off = i - 737280; }
  float4v v = *(const float4v*)(s + (size_t)off * 4);
  ushort4v o;
  o[0] = f2bf(v[0]); o[1] = f2bf(v[1]); o[2] = f2bf(v[2]); o[3] = f2bf(v[3]);
  *(ushort4v*)(d + (size_t)i * 4) = o;
}

// ---------------- GroupNorm + transpose -> xn_t[b][t][c] bf16 ----------------
__global__ __launch_bounds__(256) void k_gn(const float* __restrict__ x,
                                            const float* __restrict__ gw,
                                            const float* __restrict__ gb,
                                            unsigned short* __restrict__ xnt) {
  int g = blockIdx.x, b = blockIdx.y, tid = threadIdx.x;
  const float* xb = x + ((size_t)b * 768 + g * 24) * 1024;
  float s = 0.f, ss = 0.f;
  for (int i = tid; i < 6144; i += 256) {
    float4v v = *(const float4v*)(xb + (size_t)i * 4);
    s += v[0] + v[1] + v[2] + v[3];
    ss += v[0] * v[0] + v[1] * v[1] + v[2] * v[2] + v[3] * v[3];
  }
  #pragma unroll
  for (int o = 32; o > 0; o >>= 1) { s += __shfl_down(s, o); ss += __shfl_down(ss, o); }
  __shared__ float rs[4], rss[4], stat[2];
  int w = tid >> 6;
  if ((tid & 63) == 0) { rs[w] = s; rss[w] = ss; }
  __syncthreads();
  if (tid == 0) {
    float S = rs[0] + rs[1] + rs[2] + rs[3], SS = rss[0] + rss[1] + rss[2] + rss[3];
    float mean = S / 24576.f;
    float var = SS / 24576.f - mean * mean;
    stat[0] = mean; stat[1] = rsqrtf(fmaxf(var, 0.f) + 1e-5f);
  }
  __syncthreads();
  float mean = stat[0], rstd = stat[1];
  float wv[24], bv[24];
  #pragma unroll
  for (int c = 0; c < 24; ++c) { wv[c] = gw[g * 24 + c]; bv[c] = gb[g * 24 + c]; }
  for (int it = 0; it < 4; ++it) {
    int t = it * 256 + tid;
    ushort8v ov[3];
    #pragma unroll
    for (int c = 0; c < 24; ++c) {
      float v = xb[(size_t)c * 1024 + t];
      ov[c >> 3][c & 7] = f2bf((v - mean) * rstd * wv[c] + bv[c]);
    }
    ushort8v* dst = (ushort8v*)(xnt + ((size_t)(b * 1024 + t)) * 768 + g * 24);
    dst[0] = ov[0]; dst[1] = ov[1]; dst[2] = ov[2];
  }
}

// ---------------- encoder transpose -> enc_t[b][s][c] bf16 ----------------
__global__ __launch_bounds__(256) void k_enc_tr(const float* __restrict__ enc,
                                                unsigned short* __restrict__ et) {
  int ct = blockIdx.x * 64, st = blockIdx.y * 64, b = blockIdx.z, tid = threadIdx.x;
  __shared__ unsigned short L[64 * 72];
  #pragma unroll
  for (int it = 0; it < 4; ++it) {
    int idx = it * 256 + tid; int r = idx >> 4, ch = idx & 15;
    float4v v = *(const float4v*)(enc + ((size_t)(b * 768 + ct + r)) * 256 + st + ch * 4);
    ushort4v o;
    o[0] = f2bf(v[0]); o[1] = f2bf(v[1]); o[2] = f2bf(v[2]); o[3] = f2bf(v[3]);
    *(ushort4v*)&L[r * 72 + ch * 4] = o;
  }
  __syncthreads();
  #pragma unroll
  for (int it = 0; it < 2; ++it) {
    int idx = it * 256 + tid; int s = idx >> 3, ch = idx & 7;
    ushort8v o;
    #pragma unroll
    for (int j = 0; j < 8; ++j) o[j] = L[(ch * 8 + j) * 72 + s];
    *(ushort8v*)(et + ((size_t)(b * 256 + st + s)) * 768 + ct + ch * 8) = o;
  }
}

// ---------------- build vcat[bh][c][s] bf16 ----------------
__global__ __launch_bounds__(256) void k_vcat(const unsigned short* __restrict__ qkvt,
                                              const unsigned short* __restrict__ ekvt,
                                              unsigned short* __restrict__ vcat) {
  int s0 = blockIdx.x * 64, bh = blockIdx.y, b = bh / 12, h = bh % 12, tid = threadIdx.x;
  __shared__ unsigned short L[64 * 72];
  #pragma unroll
  for (int it = 0; it < 2; ++it) {
    int idx = it * 256 + tid; int s = idx >> 3, ch = idx & 7;
    int sg = s0 + s;
    const unsigned short* src = (sg < 256)
        ? ekvt + ((size_t)(b * 256 + sg)) * 1536 + h * 128 + 64 + ch * 8
        : qkvt + ((size_t)(b * 1024 + sg - 256)) * 2304 + h * 192 + 128 + ch * 8;
    *(ushort8v*)&L[s * 72 + ch * 8] = *(const ushort8v*)src;
  }
  __syncthreads();
  #pragma unroll
  for (int it = 0; it < 2; ++it) {
    int idx = it * 256 + tid; int c = idx >> 3, ch = idx & 7;
    ushort8v o;
    #pragma unroll
    for (int j = 0; j < 8; ++j) o[j] = L[(ch * 8 + j) * 72 + c];
    *(ushort8v*)(vcat + ((size_t)bh * 64 + c) * 1280 + s0 + ch * 8) = o;
  }
}

// ------ GEMM: C[M][N] = A[M][K]*B[N][K]^T, BK=64, 2-phase dbuf, gload_lds ------
// EPI 0: out bf16, bias[col]   EPI 1: out fp32, bias[row] + resid
template <int EPI>
__global__ __launch_bounds__(256, 2) void k_gemm(const unsigned short* __restrict__ A,
                                                 const unsigned short* __restrict__ B,
                                                 const float* __restrict__ bias,
                                                 const float* __restrict__ resid,
                                                 void* __restrict__ outp,
                                                 int N, int K,
                                                 long sA, long sB, long sO, long sR) {
  int bz = blockIdx.z;
  int m0 = blockIdx.x * 128, n0 = blockIdx.y * 128;
  const unsigned short* Ab = A + (size_t)bz * sA + (size_t)m0 * K;
  const unsigned short* Bb = B + (size_t)bz * sB + (size_t)n0 * K;
  __shared__ unsigned short As[2][8192], Bs[2][8192];  // 64 KB total
  int tid = threadIdx.x, lane = tid & 63, w = tid >> 6;
  int ln = lane & 15, lg = lane >> 4;
  int wm = (w >> 1) * 64, wn = (w & 1) * 64;
  // staging: thread covers rows (it*32 + tid>>3), chunk pre-swizzled (^ row&7)
  int srow = tid >> 3;
  int schunk = ((tid & 7) ^ (srow & 7)) * 8;
  const unsigned short* gA = Ab + (size_t)srow * K + schunk;
  const unsigned short* gB = Bb + (size_t)srow * K + schunk;

  f32x4 acc[4][4];
  #pragma unroll
  for (int i = 0; i < 4; ++i)
    #pragma unroll
    for (int j = 0; j < 4; ++j) acc[i][j] = (f32x4){0.f, 0.f, 0.f, 0.f};

  auto stageAB = [&](int buf, int k0) {
    #pragma unroll
    for (int it = 0; it < 4; ++it)
      gload16(gA + (size_t)it * 32 * K + k0, &As[buf][it * 2048 + w * 512]);
    #pragma unroll
    for (int it = 0; it < 4; ++it)
      gload16(gB + (size_t)it * 32 * K + k0, &Bs[buf][it * 2048 + w * 512]);
  };

  stageAB(0, 0);
  asm volatile("s_waitcnt vmcnt(0)" ::: "memory");
  __syncthreads();

  int nk = K >> 6;  // 12
  for (int kt = 0; kt < nk; ++kt) {
    int cur = kt & 1;
    if (kt + 1 < nk) stageAB(cur ^ 1, (kt + 1) * 64);  // async across compute
    #pragma unroll
    for (int kk = 0; kk < 2; ++kk) {
      bf16x8 af[4], bfv[4];
      #pragma unroll
      for (int i = 0; i < 4; ++i)
        af[i] = *(const bf16x8*)&As[cur][(wm + i * 16 + ln) * 64 + (((kk * 4 + lg) ^ (ln & 7)) * 8)];
      #pragma unroll
      for (int j = 0; j < 4; ++j)
        bfv[j] = *(const bf16x8*)&Bs[cur][(wn + j * 16 + ln) * 64 + (((kk * 4 + lg) ^ (ln & 7)) * 8)];
      __builtin_amdgcn_s_setprio(1);
      #pragma unroll
      for (int i = 0; i < 4; ++i)
        #pragma unroll
        for (int j = 0; j < 4; ++j)
          acc[i][j] = __builtin_amdgcn_mfma_f32_16x16x32_bf16(af[i], bfv[j], acc[i][j], 0, 0, 0);
      __builtin_amdgcn_s_setprio(0);
    }
    if (kt + 1 < nk) asm volatile("s_waitcnt vmcnt(0)" ::: "memory");
    __syncthreads();
  }

  #pragma unroll
  for (int i = 0; i < 4; ++i) {
    #pragma unroll
    for (int j = 0; j < 4; ++j) {
      #pragma unroll
      for (int r = 0; r < 4; ++r) {
        int row = m0 + wm + i * 16 + lg * 4 + r;
        int col = n0 + wn + j * 16 + ln;
        float v = acc[i][j][r];
        if (EPI == 0) {
          v += bias[col];
          ((unsigned short*)outp)[(size_t)bz * sO + (size_t)row * N + col] = f2bf(v);
        } else {
          v += bias[row] + resid[(size_t)bz * sR + (size_t)row * N + col];
          ((float*)outp)[(size_t)bz * sO + (size_t)row * N + col] = v;
        }
      }
    }
  }
}

// ---------------- attention: swapped QK, SPECULATIVE in-reg softmax ----------------
// 4 warps x QBLK=32, KVBLK=64, 32x32x16. Lane q=lane&31 owns a row; exp runs
// immediately after QK with current m; max-check deferred to after PV (exact:
// uniform rescale of acc/l, m updated for future tiles).
__global__ __launch_bounds__(256, 3) void k_attn(const unsigned short* __restrict__ qkvt,
                                                 const unsigned short* __restrict__ ekvt,
                                                 const unsigned short* __restrict__ vcat,
                                                 unsigned short* __restrict__ at) {
  int bid = blockIdx.x;
  int swb = (bid & 7) * 96 + (bid >> 3);  // XCD-contiguous head groups
  int t0 = (swb & 7) * 128, bh = swb >> 3, b = bh / 12, h = bh % 12;
  int tid = threadIdx.x, w = tid >> 6, lane = tid & 63;
  int ql = lane & 31, hi = lane >> 5;
  __shared__ unsigned short Ks[2][4096], Vs[2][4096];

  const float QSC = 0.125f * 1.44269504089f;
  bf16x8 aq[4];
  const unsigned short* qrow = qkvt + ((size_t)(b * 1024 + t0 + w * 32 + ql)) * 2304 + h * 192;
  #pragma unroll
  for (int jc = 0; jc < 4; ++jc) {
    ushort8v qv = *(const ushort8v*)(qrow + jc * 16 + hi * 8);
    bf16x8 o;
    #pragma unroll
    for (int e = 0; e < 8; ++e) o[e] = (short)f2bf(bf2f(qv[e]) * QSC);
    aq[jc] = o;
  }

  int rloc = w * 16 + (lane >> 3);
  int chunk = (lane & 7) ^ (lane >> 3);
  const unsigned short* ke_st = ekvt + ((size_t)(b * 256 + rloc)) * 1536 + h * 128 + chunk * 8;
  const unsigned short* kq_st = qkvt + ((long)b * 1024 - 256 + rloc) * 2304 + h * 192 + 64 + chunk * 8;
  const unsigned short* v_st  = vcat + ((size_t)(bh * 64 + rloc)) * 1280 + chunk * 8;
  unsigned short* kd = &Ks[0][0] + w * 1024;
  unsigned short* vd = &Vs[0][0] + w * 1024;

  auto stage = [&](int nb, int tn) {
    const unsigned short* ks;
    size_t rstep;
    if (tn < 4) { ks = ke_st + (size_t)tn * 64 * 1536; rstep = 8 * 1536; }
    else        { ks = kq_st + (size_t)tn * 64 * 2304; rstep = 8 * 2304; }
    unsigned short* kdd = kd + nb * 4096;
    unsigned short* vdd = vd + nb * 4096;
    const unsigned short* vs = v_st + tn * 64;
    gload16(ks, kdd);
    gload16(ks + rstep, kdd + 512);
    gload16(vs, vdd);
    gload16(vs + 8 * 1280, vdd + 512);
  };

  stage(0, 0);
  asm volatile("s_waitcnt vmcnt(0)" ::: "memory");
  __syncthreads();

  f32x16 acc0, acc1;
  #pragma unroll
  for (int r = 0; r < 16; ++r) { acc0[r] = 0.f; acc1[r] = 0.f; }
  float m = 0.f, l = 0.f;  // m=0 safe: scores O(1); deferred check corrects drift
  int xp = (ql & 7) << 4;

  for (int t = 0; t < 20; ++t) {
    int cur = t & 1;
    if (t < 19) stage(cur ^ 1, t + 1);

    // QK^T (swapped): sf = P^T[s][q]
    f32x16 sf0, sf1;
    #pragma unroll
    for (int r = 0; r < 16; ++r) { sf0[r] = 0.f; sf1[r] = 0.f; }
    const char* kbase = (const char*)&Ks[cur][0] + ql * 128;
    __builtin_amdgcn_s_setprio(1);
    #pragma unroll
    for (int jc = 0; jc < 4; ++jc) {
      int off = (jc * 32 + hi * 16) ^ xp;
      bf16x8 k0f = *(const bf16x8*)(kbase + off);
      bf16x8 k1f = *(const bf16x8*)(kbase + 4096 + off);
      sf0 = __builtin_amdgcn_mfma_f32_32x32x16_bf16(k0f, aq[jc], sf0, 0, 0, 0);
      sf1 = __builtin_amdgcn_mfma_f32_32x32x16_bf16(k1f, aq[jc], sf1, 0, 0, 0);
    }
    __builtin_amdgcn_s_setprio(0);

    // speculative exp with current m (critical path: no max tree here)
    float pe[32];
    #pragma unroll
    for (int i = 0; i < 16; ++i) pe[i] = exp2a(sf0[i] - m);
    #pragma unroll
    for (int i = 0; i < 16; ++i) pe[16 + i] = exp2a(sf1[i] - m);

    // pack -> permlane exchange -> PV
    const char* vbase = (const char*)&Vs[cur][0] + ql * 128;
    #pragma unroll
    for (int sb = 0; sb < 2; ++sb) {
      unsigned pk[8];
      #pragma unroll
      for (int i = 0; i < 8; ++i)
        pk[i] = cvtpk(pe[sb * 16 + 2 * i], pe[sb * 16 + 2 * i + 1]);
      plswap(pk[0], pk[2]);
      plswap(pk[1], pk[3]);
      plswap(pk[4], pk[6]);
      plswap(pk[5], pk[7]);
      bf16x8 fj0 = mkfrag(pk[0], pk[1], pk[2], pk[3]);
      bf16x8 fj1 = mkfrag(pk[4], pk[5], pk[6], pk[7]);
      __builtin_amdgcn_s_setprio(1);
      #pragma unroll
      for (int jj = 0; jj < 2; ++jj) {
        int off = (sb * 64 + jj * 32 + hi * 16) ^ xp;
        bf16x8 v0f = *(const bf16x8*)(vbase + off);
        bf16x8 v1f = *(const bf16x8*)(vbase + 4096 + off);
        bf16x8 pf = jj ? fj1 : fj0;
        acc0 = __builtin_amdgcn_mfma_f32_32x32x16_bf16(v0f, pf, acc0, 0, 0, 0);
        acc1 = __builtin_amdgcn_mfma_f32_32x32x16_bf16(v1f, pf, acc1, 0, 0, 0);
      }
      __builtin_amdgcn_s_setprio(0);
    }

    // l accumulation (ILP tree)
    float s0 = 0.f, s1 = 0.f, s2 = 0.f, s3 = 0.f;
    #pragma unroll
    for (int i = 0; i < 8; ++i) {
      s0 += pe[i]; s1 += pe[8 + i]; s2 += pe[16 + i]; s3 += pe[24 + i];
    }
    l += (s0 + s1) + (s2 + s3);

    // deferred stability check (off critical path; corrects future tiles)
    float mx[8];
    #pragma unroll
    for (int i = 0; i < 8; ++i)
      mx[i] = fmaxf(fmaxf(pe[i], pe[i + 8]), fmaxf(pe[i + 16], pe[i + 24]));
    #pragma unroll
    for (int o = 4; o > 0; o >>= 1)
      #pragma unroll
      for (int i = 0; i < 4; ++i)
        if (i < o) mx[i] = fmaxf(mx[i], mx[i + o]);
    float pmax = fmaxf(mx[0], __shfl_xor(mx[0], 32));
    if (!__all(pmax <= 256.f)) {  // pe_max = 2^(mt-m) > 2^8  (rare)
      float mn = m + __log2f(fmaxf(pmax, 1.f));
      float al = exp2a(m - mn);
      l *= al;
      #pragma unroll
      for (int r = 0; r < 16; ++r) { acc0[r] *= al; acc1[r] *= al; }
      m = mn;
    }

    if (t < 19) asm volatile("s_waitcnt vmcnt(0)" ::: "memory");
    __syncthreads();
  }

  l += __shfl_xor(l, 32);
  float rl = 1.f / l;
  unsigned short* orow = at + ((size_t)(b * 1024 + t0 + w * 32 + ql)) * 768 + h * 64;
  #pragma unroll
  for (int cb = 0; cb < 2; ++cb) {
    #pragma unroll
    for (int g = 0; g < 4; ++g) {
      int c = cb * 32 + g * 8 + hi * 4;
      ushort4v o;
      #pragma unroll
      for (int i = 0; i < 4; ++i) {
        float v = (cb ? acc1[g * 4 + i] : acc0[g * 4 + i]) * rl;
        o[i] = f2bf(v);
      }
      *(ushort4v*)(orow + c) = o;
    }
  }
}

// ---------------- launch ----------------
extern "C" void kernel_launch(void* const* d_in, const int* in_sizes, int n_in,
                              void* d_out, int out_size, void* d_ws, size_t ws_size,
                              hipStream_t stream) {
  const float* x      = (const float*)d_in[0];
  const float* enc    = (const float*)d_in[1];
  const float* gn_w   = (const float*)d_in[2];
  const float* gn_b   = (const float*)d_in[3];
  const float* qkv_w  = (const float*)d_in[4];
  const float* qkv_b  = (const float*)d_in[5];
  const float* enc_w  = (const float*)d_in[6];
  const float* enc_b  = (const float*)d_in[7];
  const float* proj_w = (const float*)d_in[8];
  const float* proj_b = (const float*)d_in[9];
  float* out = (float*)d_out;

  char* ws = (char*)d_ws;
  unsigned short* w_qkv = (unsigned short*)(ws + 0);
  unsigned short* w_enc = (unsigned short*)(ws + 3538944);
  unsigned short* w_prj = (unsigned short*)(ws + 5898240);
  unsigned short* xn_t  = (unsigned short*)(ws + 7077888);
  unsigned short* enc_t = (unsigned short*)(ws + 19660800);
  unsigned short* qkv_t = (unsigned short*)(ws + 22806528);
  unsigned short* ekv_t = (unsigned short*)(ws + 60555264);
  unsigned short* vcat  = (unsigned short*)(ws + 66846720);
  unsigned short* a_t   = xn_t;

  k_cvt3<<<3456, 256, 0, stream>>>(qkv_w, enc_w, proj_w, w_qkv);
  k_gn<<<dim3(32, 8), 256, 0, stream>>>(x, gn_w, gn_b, xn_t);
  k_enc_tr<<<dim3(12, 4, 8), 256, 0, stream>>>(enc, enc_t);
  // GEMM1 fused over batch: 8192 x 2304 x 768
  k_gemm<0><<<dim3(64, 18, 1), 256, 0, stream>>>(xn_t, w_qkv, qkv_b, nullptr, qkv_t,
                                                 2304, 768, 0L, 0L, 0L, 0L);
  // GEMM2 fused: 2048 x 1536 x 768
  k_gemm<0><<<dim3(16, 12, 1), 256, 0, stream>>>(enc_t, w_enc, enc_b, nullptr, ekv_t,
                                                 1536, 768, 0L, 0L, 0L, 0L);
  k_vcat<<<dim3(20, 96), 256, 0, stream>>>(qkv_t, ekv_t, vcat);
  k_attn<<<dim3(768), 256, 0, stream>>>(qkv_t, ekv_t, vcat, a_t);
  // GEMM3: out[b][o][t] = proj(a) + bias + x ; per-batch 768 x 1024 x 768
  k_gemm<1><<<dim3(6, 8, 8), 256, 0, stream>>>(w_prj, a_t, proj_b, x, out,
                                               1024, 768, 0L, 786432L, 786432L, 786432L);
}